// Round 3
// baseline (706.219 us; speedup 1.0000x reference)
//
#include <hip/hip_runtime.h>
#include <hip/hip_bf16.h>
#include <stdint.h>

typedef unsigned short u16;
typedef unsigned int   u32;
typedef __attribute__((ext_vector_type(8))) short short8;   // 8 bf16 = MFMA A/B frag
typedef __attribute__((ext_vector_type(4))) float f32x4;    // MFMA C/D frag
typedef __attribute__((ext_vector_type(2))) u32   u32x2;
typedef __attribute__((ext_vector_type(4))) u32   u32x4;

#define DEV static __device__ __forceinline__

constexpr int N_  = 10000;
constexpr int T_  = 32;
constexpr int E_  = 320000;
constexpr int E2_ = 160000;

DEV u16 f2bf(float f) {
    union { float f; u32 u; } v; v.f = f;
    u32 u = v.u;
    return (u16)((u + 0x7fffu + ((u >> 16) & 1u)) >> 16);   // RNE
}
DEV float bf2f(u16 h) {
    union { u32 u; float f; } v; v.u = ((u32)h) << 16; return v.f;
}
DEV float lrelu(float x) { return x > 0.f ? x : 0.01f * x; }

DEV float fexp2(float x) {
#if __has_builtin(__builtin_amdgcn_exp2f)
    return __builtin_amdgcn_exp2f(x);
#else
    return exp2f(x);
#endif
}
DEV float frcp(float x) {
#if __has_builtin(__builtin_amdgcn_rcpf)
    return __builtin_amdgcn_rcpf(x);
#else
    return 1.0f / x;
#endif
}
DEV float fsig(float x)  { return frcp(1.f + fexp2(-1.4426950408889634f * x)); }
DEV float ftanh_(float x){ return 1.f - 2.f * frcp(1.f + fexp2(2.8853900817779268f * x)); }

// ---------------------------------------------------------------------------
// xtab[dir][sym][512] = emb_url[sym] @ Wih.T + b   (bf16)
// ---------------------------------------------------------------------------
__global__ void k_xtab(const float* __restrict__ emb,
                       const float* __restrict__ WihF, const float* __restrict__ bF,
                       const float* __restrict__ WihB, const float* __restrict__ bB,
                       u16* __restrict__ xtab) {
    int sym = blockIdx.x, dir = blockIdx.y, o = threadIdx.x;   // block 512
    const float* W = dir ? WihB : WihF;
    const float* b = dir ? bB : bF;
    __shared__ float er[128];
    if (o < 128) er[o] = emb[sym * 128 + o];
    __syncthreads();
    float s = b[o];
    for (int k = 0; k < 128; k++) s += er[k] * W[o * 128 + k];
    xtab[((size_t)(dir * 128 + sym)) * 512 + o] = f2bf(s);
}

// ---------------------------------------------------------------------------
// Weight transpose+convert: W fp32 [S][K][Nw] -> out bf16 [S][Nw][K]
// ---------------------------------------------------------------------------
__global__ void k_wt(const float* __restrict__ W, u16* __restrict__ out,
                     int S, int K, int Nw) {
    int i = blockIdx.x * 256 + threadIdx.x;
    int tot = S * Nw * K;
    if (i >= tot) return;
    int k = i % K, n = (i / K) % Nw, s = i / (K * Nw);
    out[i] = f2bf(W[((size_t)s * K + k) * Nw + n]);
}

// ---------------------------------------------------------------------------
// Bi-LSTM: block = 512 threads (8 waves) x 16 sequences, one direction.
// Wave w owns hidden units [16w,16w+16) for all 4 gates (64 VGPR of Whh).
// h in LDS in MFMA-fragment-major layout, double-buffered; one barrier/step.
// launch_bounds(512,2): 128-VGPR cap -> NO spill (R2's (512,4) forced a
// 64-VGPR cap and 232 MB/dispatch of scratch traffic).
// sym/msk tables transposed to [t][seq] (R2 layout was a 16-way bank conflict).
// ---------------------------------------------------------------------------
__global__ __launch_bounds__(512, 2) void k_lstm(
    const u16* __restrict__ xtab,      // [2][128][512] bf16 (bias folded)
    const int* __restrict__ syms,      // [N][32]
    const int* __restrict__ smask,     // [N][32]
    const float* __restrict__ WhhF,    // [512][128]
    const float* __restrict__ WhhB,
    u16* __restrict__ hcat)            // [N][256] bf16 (fwd | bwd)
{
    __shared__ u16 h_buf[2][2048];     // [16 slabs][16 seq][8 elems]
    __shared__ int sym_l[512];         // [t][seq]
    __shared__ int msk_l[512];         // [t][seq]

    int tid = threadIdx.x;
    int w = tid >> 6, l = tid & 63, l15 = l & 15, lg = l >> 4;
    int dir = blockIdx.y;
    int n0 = blockIdx.x * 16;
    const float* Whh = dir ? WhhB : WhhF;

    for (int i = tid; i < 512; i += 512) {
        int seq = i >> 5, t = i & 31;
        sym_l[t * 16 + seq] = syms[(size_t)n0 * 32 + i];
        msk_l[t * 16 + seq] = smask[(size_t)n0 * 32 + i];
    }
    for (int i = tid; i < 2048; i += 512) h_buf[0][i] = 0;

    // A fragments: wave w covers gate gg, units 128*gg + 16*w + row
    short8 aw[4][4];
#pragma unroll
    for (int gg = 0; gg < 4; gg++)
#pragma unroll
    for (int kk = 0; kk < 4; kk++) {
        const float* p = Whh + (size_t)(128 * gg + 16 * w + l15) * 128 + 32 * kk + 8 * lg;
        const float4* pp = (const float4*)p;
        float4 x0 = pp[0], x1 = pp[1];
        short8 v;
        v[0] = (short)f2bf(x0.x); v[1] = (short)f2bf(x0.y);
        v[2] = (short)f2bf(x0.z); v[3] = (short)f2bf(x0.w);
        v[4] = (short)f2bf(x1.x); v[5] = (short)f2bf(x1.y);
        v[6] = (short)f2bf(x1.z); v[7] = (short)f2bf(x1.w);
        aw[gg][kk] = v;
    }

    float hreg[4] = {0, 0, 0, 0};
    float creg[4] = {0, 0, 0, 0};
    int jb = 16 * w + 4 * lg;          // hidden-unit base for this lane
    int wsk = 2 * w + (lg >> 1);       // write slab index (= jb>>3)
    int wof = (wsk * 16 + l15) * 8 + 4 * (lg & 1);
    __syncthreads();

    for (int st = 0; st < 32; st++) {
        const u16* rb = h_buf[st & 1];
        u16* wb = h_buf[(st & 1) ^ 1];
        int t = dir ? (31 - st) : st;
        int sym = sym_l[t * 16 + l15];
        float mt = (float)msk_l[t * 16 + l15];

        // xtab gate-input prefetch (independent of LDS; overlaps MFMA)
        const u16* xrow = xtab + ((size_t)(dir * 128 + sym)) * 512 + jb;
        u32x2 xt[4];
#pragma unroll
        for (int gg = 0; gg < 4; gg++)
            xt[gg] = *(const u32x2*)(xrow + gg * 128);

        // B fragments: contiguous 1KB slab per wave, conflict-free
        short8 bh[4];
#pragma unroll
        for (int kk = 0; kk < 4; kk++)
            bh[kk] = *(const short8*)&rb[((kk * 4 + lg) * 16 + l15) * 8];

        f32x4 acc[4];
#pragma unroll
        for (int gg = 0; gg < 4; gg++) {
            f32x4 a = {0.f, 0.f, 0.f, 0.f};
#pragma unroll
            for (int kk = 0; kk < 4; kk++)
                a = __builtin_amdgcn_mfma_f32_16x16x32_bf16(aw[gg][kk], bh[kk], a, 0, 0, 0);
            acc[gg] = a;
        }

        u16 hp[4];
#pragma unroll
        for (int r = 0; r < 4; r++) {
            u32 wi = xt[0][r >> 1], wf = xt[1][r >> 1], wg = xt[2][r >> 1], wo = xt[3][r >> 1];
            float gi = acc[0][r] + bf2f((r & 1) ? (u16)(wi >> 16) : (u16)wi);
            float gf = acc[1][r] + bf2f((r & 1) ? (u16)(wf >> 16) : (u16)wf);
            float gc = acc[2][r] + bf2f((r & 1) ? (u16)(wg >> 16) : (u16)wg);
            float go = acc[3][r] + bf2f((r & 1) ? (u16)(wo >> 16) : (u16)wo);
            float i_ = fsig(gi), f_ = fsig(gf), g_ = ftanh_(gc), o_ = fsig(go);
            float cn = f_ * creg[r] + i_ * g_;
            float hn = o_ * ftanh_(cn);
            float hN = mt * hn + (1.f - mt) * hreg[r];
            float cN = mt * cn + (1.f - mt) * creg[r];
            hreg[r] = hN; creg[r] = cN;
            hp[r] = f2bf(hN);
        }
        u32x2 pk; pk[0] = (u32)hp[0] | ((u32)hp[1] << 16); pk[1] = (u32)hp[2] | ((u32)hp[3] << 16);
        *(u32x2*)&wb[wof] = pk;
        __syncthreads();   // writes to wb visible before next step reads it
    }

    // final hidden -> hcat[n][dir*128 + j]
    {
        u16 hp[4];
#pragma unroll
        for (int r = 0; r < 4; r++) hp[r] = f2bf(hreg[r]);
        u32x2 pk; pk[0] = (u32)hp[0] | ((u32)hp[1] << 16); pk[1] = (u32)hp[2] | ((u32)hp[3] << 16);
        *(u32x2*)&hcat[(size_t)(n0 + l15) * 256 + dir * 128 + jb] = pk;
    }
}

// ---------------------------------------------------------------------------
// Generic MFMA GEMM: C[M,128] = act(A1@B1 [+ A2@B2] + bias), bf16 in/out.
// B pre-transposed bf16 [128][K]. Block = 4 waves x 16 rows.
// blockIdx.y = stream index s; so* are per-stream element offsets.
// ---------------------------------------------------------------------------
template<int ACT, int DUAL>
__global__ __launch_bounds__(256) void k_gemm(
    const u16* __restrict__ A1, int lda1, int soA1,
    const u16* __restrict__ A2, int lda2, int soA2,
    const u16* __restrict__ B1, int soB1,
    const u16* __restrict__ B2, int soB2,
    const float* __restrict__ bias, int soBias,
    u16* __restrict__ C, int ldc, int soC, int M, int K)
{
    int s = blockIdx.y;
    A1 += (size_t)s * soA1;
    if (DUAL) A2 += (size_t)s * soA2;
    B1 += (size_t)s * soB1;
    if (DUAL) B2 += (size_t)s * soB2;
    if (bias) bias += (size_t)s * soBias;
    C += (size_t)s * soC;

    int tid = threadIdx.x;
    int w = tid >> 6, l = tid & 63, l15 = l & 15, lg = l >> 4;
    int mbase = blockIdx.x * 64 + w * 16;
    int arow = mbase + l15; if (arow >= M) arow = M - 1;

    f32x4 acc[8];
#pragma unroll
    for (int nt = 0; nt < 8; nt++) {
        float bv = bias ? bias[16 * nt + l15] : 0.f;
        acc[nt] = (f32x4){bv, bv, bv, bv};
    }
    for (int k0 = 0; k0 < K; k0 += 32) {
        int k = k0 + 8 * lg;
        short8 a1 = *(const short8*)&A1[(size_t)arow * lda1 + k];
        short8 a2;
        if (DUAL) a2 = *(const short8*)&A2[(size_t)arow * lda2 + k];
#pragma unroll
        for (int nt = 0; nt < 8; nt++) {
            short8 b1 = *(const short8*)&B1[(size_t)(16 * nt + l15) * K + k];
            acc[nt] = __builtin_amdgcn_mfma_f32_16x16x32_bf16(a1, b1, acc[nt], 0, 0, 0);
            if (DUAL) {
                short8 b2 = *(const short8*)&B2[(size_t)(16 * nt + l15) * K + k];
                acc[nt] = __builtin_amdgcn_mfma_f32_16x16x32_bf16(a2, b2, acc[nt], 0, 0, 0);
            }
        }
    }
#pragma unroll
    for (int nt = 0; nt < 8; nt++)
#pragma unroll
    for (int r = 0; r < 4; r++) {
        int m = mbase + 4 * lg + r;
        if (m < M) {
            float v = acc[nt][r];
            if (ACT == 1) v = lrelu(v);
            C[(size_t)m * ldc + 16 * nt + l15] = f2bf(v);
        }
    }
}

// ---------------------------------------------------------------------------
// F0 packing: embedding gathers + ip  (cols 128..543; cols 0..127 by gemm)
// ---------------------------------------------------------------------------
__global__ void k_pack(const int* __restrict__ ic, const int* __restrict__ ico,
                       const int* __restrict__ isl, const float* __restrict__ ip,
                       const float* __restrict__ ecat, const float* __restrict__ ecou,
                       const float* __restrict__ esl, u16* __restrict__ F0) {
    int n = blockIdx.x, t = threadIdx.x;   // block 128
    u16* row = F0 + (size_t)n * 544;
    row[128 + t] = f2bf(ecat[(size_t)ic[n]  * 128 + t]);
    row[256 + t] = f2bf(ecou[(size_t)ico[n] * 128 + t]);
    row[384 + t] = f2bf(esl [(size_t)isl[n] * 128 + t]);
    if (t < 32) row[512 + t] = f2bf(ip[(size_t)n * 32 + t]);
}

// ---------------------------------------------------------------------------
// CSR build
// ---------------------------------------------------------------------------
__global__ void k_hist(const int* __restrict__ dst, int E, int* __restrict__ deg) {
    int e = blockIdx.x * 256 + threadIdx.x;
    if (e < E) atomicAdd(&deg[dst[e]], 1);
}
__global__ void k_scan(const int* __restrict__ deg, int* __restrict__ rowptr,
                       int* __restrict__ cursor, int n) {
    __shared__ int part[1024];
    int tid = threadIdx.x;
    const int CH = 10;
    int base = tid * CH;
    int s = 0;
#pragma unroll
    for (int i = 0; i < CH; i++) { int idx = base + i; if (idx < n) s += deg[idx]; }
    part[tid] = s; __syncthreads();
    for (int off = 1; off < 1024; off <<= 1) {
        int v = (tid >= off) ? part[tid - off] : 0;
        __syncthreads();
        part[tid] += v;
        __syncthreads();
    }
    int run = part[tid] - s;
    for (int i = 0; i < CH; i++) {
        int idx = base + i;
        if (idx < n) { rowptr[idx] = run; cursor[idx] = run; run += deg[idx]; }
    }
    if (tid == 1023) rowptr[n] = part[1023];
}
__global__ void k_fill(const int* __restrict__ src, const int* __restrict__ dst, int E,
                       int* __restrict__ cursor, int* __restrict__ colsrc) {
    int e = blockIdx.x * 256 + threadIdx.x;
    if (e < E) {
        int pos = atomicAdd(&cursor[dst[e]], 1);
        colsrc[pos] = src[e];
    }
}

// ---------------------------------------------------------------------------
// Mean aggregation: wave per node, uint4-chunked bf16 rows.
// ---------------------------------------------------------------------------
__global__ __launch_bounds__(256) void k_agg(const u16* __restrict__ F, int C,
                                             const int* __restrict__ rowptr,
                                             const int* __restrict__ colsrc,
                                             u16* __restrict__ out, int N) {
    int w = threadIdx.x >> 6, l = threadIdx.x & 63;
    int n = blockIdx.x * 4 + w;
    if (n >= N) return;
    int chunks = C >> 3;
    int c0 = l, c1 = l + 64;
    bool has1 = c1 < chunks;
    float a0[8] = {0,0,0,0,0,0,0,0}, a1[8] = {0,0,0,0,0,0,0,0};
    int beg = rowptr[n], end = rowptr[n + 1];
    for (int e = beg; e < end; e++) {
        int s = colsrc[e];
        const u32x4* rp = (const u32x4*)(F + (size_t)s * C);
        u32x4 v0 = rp[c0];
#pragma unroll
        for (int j = 0; j < 4; j++) {
            u32 u = v0[j];
            a0[2*j]   += bf2f((u16)u);
            a0[2*j+1] += bf2f((u16)(u >> 16));
        }
        if (has1) {
            u32x4 v1 = rp[c1];
#pragma unroll
            for (int j = 0; j < 4; j++) {
                u32 u = v1[j];
                a1[2*j]   += bf2f((u16)u);
                a1[2*j+1] += bf2f((u16)(u >> 16));
            }
        }
    }
    int dg = end - beg; if (dg < 1) dg = 1;
    float inv = 1.f / (float)dg;
    u32x4 o0;
#pragma unroll
    for (int j = 0; j < 4; j++)
        o0[j] = (u32)f2bf(a0[2*j] * inv) | ((u32)f2bf(a0[2*j+1] * inv) << 16);
    ((u32x4*)(out + (size_t)n * C))[c0] = o0;
    if (has1) {
        u32x4 o1;
#pragma unroll
        for (int j = 0; j < 4; j++)
            o1[j] = (u32)f2bf(a1[2*j] * inv) | ((u32)f2bf(a1[2*j+1] * inv) << 16);
        ((u32x4*)(out + (size_t)n * C))[c1] = o1;
    }
}

// ---------------------------------------------------------------------------
// Attention fusion: wave per node. logits -> softmax(5) -> a, h = sum a*z.
// (attn_b is a constant shift -> softmax-invariant, skipped.)
// ---------------------------------------------------------------------------
__global__ __launch_bounds__(256) void k_attn(const u16* __restrict__ Z,
                                              const float* __restrict__ attnW,
                                              float* __restrict__ aOut,
                                              u16* __restrict__ hT, int N) {
    int w = threadIdx.x >> 6, l = threadIdx.x & 63;
    int n = blockIdx.x * 4 + w;
    if (n >= N) return;
    float wa0 = attnW[l], wa1 = attnW[l + 64];
    float z0[5], z1[5], lgt[5];
#pragma unroll
    for (int s = 0; s < 5; s++) {
        z0[s] = bf2f(Z[((size_t)(n * 5 + s)) * 128 + l]);
        z1[s] = bf2f(Z[((size_t)(n * 5 + s)) * 128 + l + 64]);
        float p = z0[s] * wa0 + z1[s] * wa1;
#pragma unroll
        for (int m = 1; m < 64; m <<= 1) p += __shfl_xor(p, m, 64);
        lgt[s] = p;
    }
    float mx = lgt[0];
#pragma unroll
    for (int s = 1; s < 5; s++) mx = fmaxf(mx, lgt[s]);
    float ex[5], sum = 0.f;
#pragma unroll
    for (int s = 0; s < 5; s++) { ex[s] = __expf(lgt[s] - mx); sum += ex[s]; }
    float a[5];
#pragma unroll
    for (int s = 0; s < 5; s++) a[s] = ex[s] / sum;
    float h0 = 0.f, h1 = 0.f;
#pragma unroll
    for (int s = 0; s < 5; s++) { h0 += a[s] * z0[s]; h1 += a[s] * z1[s]; }
    hT[(size_t)n * 128 + l] = f2bf(h0);
    hT[(size_t)n * 128 + l + 64] = f2bf(h1);
    if (l == 0) {
#pragma unroll
        for (int s = 0; s < 5; s++) aOut[(size_t)n * 5 + s] = a[s];
    }
}

// ---------------------------------------------------------------------------
// Edge MLP fused: score = lrelu([h_src|h_dst]@fcW + fcb)@fcoW + fcob
// wave per 16 edges; second matmul as in-register shfl reduce.
// ---------------------------------------------------------------------------
__global__ __launch_bounds__(256) void k_edge(const u16* __restrict__ hT,
                                              const int* __restrict__ esrc,
                                              const int* __restrict__ edst,
                                              const u16* __restrict__ fcWt,  // [128][256]
                                              const float* __restrict__ fcb,
                                              const float* __restrict__ fcoW, // [128][2]
                                              const float* __restrict__ fcob,
                                              float* __restrict__ score, int E2) {
    int tid = threadIdx.x;
    int w = tid >> 6, l = tid & 63, l15 = l & 15, lg = l >> 4;
    int eb = (blockIdx.x * 4 + w) * 16;
    int arow = eb + l15; if (arow >= E2) arow = E2 - 1;
    int sn = esrc[arow], dn = edst[arow];

    f32x4 acc[8];
#pragma unroll
    for (int nt = 0; nt < 8; nt++) {
        float bv = fcb[16 * nt + l15];
        acc[nt] = (f32x4){bv, bv, bv, bv};
    }
#pragma unroll
    for (int kk = 0; kk < 8; kk++) {
        int k = 32 * kk + 8 * lg;
        const u16* ap = (k < 128) ? &hT[(size_t)sn * 128 + k]
                                  : &hT[(size_t)dn * 128 + (k - 128)];
        short8 a = *(const short8*)ap;
#pragma unroll
        for (int nt = 0; nt < 8; nt++) {
            short8 b = *(const short8*)&fcWt[(size_t)(16 * nt + l15) * 256 + k];
            acc[nt] = __builtin_amdgcn_mfma_f32_16x16x32_bf16(a, b, acc[nt], 0, 0, 0);
        }
    }
    float p0[4] = {0,0,0,0}, p1[4] = {0,0,0,0};
#pragma unroll
    for (int nt = 0; nt < 8; nt++) {
        int c = 16 * nt + l15;
        float w0 = fcoW[c * 2], w1 = fcoW[c * 2 + 1];
#pragma unroll
        for (int r = 0; r < 4; r++) {
            float hd = lrelu(acc[nt][r]);
            p0[r] += hd * w0; p1[r] += hd * w1;
        }
    }
#pragma unroll
    for (int m = 1; m < 16; m <<= 1) {
#pragma unroll
        for (int r = 0; r < 4; r++) {
            p0[r] += __shfl_xor(p0[r], m, 64);
            p1[r] += __shfl_xor(p1[r], m, 64);
        }
    }
    if (l15 == 0) {
        float b0v = fcob[0], b1v = fcob[1];
#pragma unroll
        for (int r = 0; r < 4; r++) {
            int e = eb + 4 * lg + r;
            if (e < E2) {
                score[(size_t)e * 2 + 0] = p0[r] + b0v;
                score[(size_t)e * 2 + 1] = p1[r] + b1v;
            }
        }
    }
}

// ---------------------------------------------------------------------------
// attn_e output: [E2,2,5] both rows = a[e_src]
// ---------------------------------------------------------------------------
__global__ void k_attne(const float* __restrict__ a, const int* __restrict__ esrc,
                        float* __restrict__ out, int E2) {
    int m = blockIdx.x * 256 + threadIdx.x;
    if (m >= E2) return;
    int s = esrc[m];
#pragma unroll
    for (int i = 0; i < 5; i++) {
        float v = a[(size_t)s * 5 + i];
        out[(size_t)m * 10 + i] = v;
        out[(size_t)m * 10 + 5 + i] = v;
    }
}

// ---------------------------------------------------------------------------
extern "C" void kernel_launch(void* const* d_in, const int* in_sizes, int n_in,
                              void* d_out, int out_size, void* d_ws, size_t ws_size,
                              hipStream_t stream) {
    const int* inp_s   = (const int*)d_in[0];
    const int* inp_sm  = (const int*)d_in[1];
    const int* inp_c   = (const int*)d_in[2];
    const int* inp_co  = (const int*)d_in[3];
    const int* inp_sl  = (const int*)d_in[4];
    const float* inp_ip = (const float*)d_in[5];
    const int* blk_src = (const int*)d_in[6];
    const int* blk_dst = (const int*)d_in[7];
    const int* e_src   = (const int*)d_in[8];
    const int* e_dst   = (const int*)d_in[9];
    const float* emb_url = (const float*)d_in[10];
    const float* emb_cat = (const float*)d_in[11];
    const float* emb_cou = (const float*)d_in[12];
    const float* emb_sl  = (const float*)d_in[13];
    const float* Wih_f = (const float*)d_in[14];
    const float* Whh_f = (const float*)d_in[15];
    const float* b_f   = (const float*)d_in[16];
    const float* Wih_b = (const float*)d_in[17];
    const float* Whh_b = (const float*)d_in[18];
    const float* b_b   = (const float*)d_in[19];
    const float* fc_lstm_W = (const float*)d_in[20];
    const float* fc_lstm_b = (const float*)d_in[21];
    const float* attnlin_W = (const float*)d_in[22];
    const float* attn_W    = (const float*)d_in[23];
    /* d_in[24] attn_b: softmax shift-invariant, unused */
    const float* W0_self  = (const float*)d_in[25];
    const float* W0_neigh = (const float*)d_in[26];
    const float* b0       = (const float*)d_in[27];
    const float* Wip_self  = (const float*)d_in[28];
    const float* Wip_neigh = (const float*)d_in[29];
    const float* bip       = (const float*)d_in[30];
    const float* W1_self  = (const float*)d_in[31];
    const float* W1_neigh = (const float*)d_in[32];
    const float* b1       = (const float*)d_in[33];
    const float* fc_W  = (const float*)d_in[34];
    const float* fc_b  = (const float*)d_in[35];
    const float* fco_W = (const float*)d_in[36];
    const float* fco_b = (const float*)d_in[37];

    char* ws = (char*)d_ws;
    size_t off = 0;
    auto alloc = [&](size_t bytes) -> char* {
        char* p = ws + off;
        off += (bytes + 255) & ~(size_t)255;
        return p;
    };
    u16* xtab      = (u16*)alloc((size_t)2 * 128 * 512 * 2);
    u16* hcat      = (u16*)alloc((size_t)N_ * 256 * 2);
    u16* wt_fclstm = (u16*)alloc((size_t)128 * 256 * 2);
    u16* wt_w0s    = (u16*)alloc((size_t)4 * 128 * 128 * 2);
    u16* wt_w0n    = (u16*)alloc((size_t)4 * 128 * 128 * 2);
    u16* wt_ips    = (u16*)alloc((size_t)128 * 32 * 2);
    u16* wt_ipn    = (u16*)alloc((size_t)128 * 32 * 2);
    u16* wt_w1s    = (u16*)alloc((size_t)5 * 128 * 128 * 2);
    u16* wt_w1n    = (u16*)alloc((size_t)5 * 128 * 128 * 2);
    u16* wt_attn   = (u16*)alloc((size_t)128 * 128 * 2);
    u16* wt_fc     = (u16*)alloc((size_t)128 * 256 * 2);
    u16* F0        = (u16*)alloc((size_t)N_ * 544 * 2);
    u16* NEI       = (u16*)alloc((size_t)N_ * 640 * 2);
    u16* F1        = (u16*)alloc((size_t)N_ * 640 * 2);
    u16* H1        = (u16*)alloc((size_t)N_ * 640 * 2);
    u16* Zb        = (u16*)alloc((size_t)N_ * 5 * 128 * 2);
    u16* hT        = (u16*)alloc((size_t)N_ * 128 * 2);
    float* aA      = (float*)alloc((size_t)N_ * 5 * 4);
    int* deg       = (int*)alloc((size_t)N_ * 4);
    int* rowptr    = (int*)alloc((size_t)(N_ + 1) * 4);
    int* cursor    = (int*)alloc((size_t)N_ * 4);
    int* colsrc    = (int*)alloc((size_t)E_ * 4);
    (void)ws_size; (void)in_sizes; (void)n_in; (void)out_size;

    float* out_score = (float*)d_out;
    float* out_attne = out_score + (size_t)2 * E2_;

    // --- CSR build ---
    hipMemsetAsync(deg, 0, (size_t)N_ * 4, stream);
    k_hist<<<dim3((E_ + 255) / 256), dim3(256), 0, stream>>>(blk_dst, E_, deg);
    k_scan<<<dim3(1), dim3(1024), 0, stream>>>(deg, rowptr, cursor, N_);
    k_fill<<<dim3((E_ + 255) / 256), dim3(256), 0, stream>>>(blk_src, blk_dst, E_, cursor, colsrc);

    // --- LSTM prep + run ---
    k_xtab<<<dim3(128, 2), dim3(512), 0, stream>>>(emb_url, Wih_f, b_f, Wih_b, b_b, xtab);
    auto wt = [&](const float* W, u16* o, int S, int K, int Nw) {
        int tot = S * Nw * K;
        k_wt<<<dim3((tot + 255) / 256), dim3(256), 0, stream>>>(W, o, S, K, Nw);
    };
    wt(fc_lstm_W, wt_fclstm, 1, 256, 128);
    wt(W0_self,  wt_w0s, 4, 128, 128);
    wt(W0_neigh, wt_w0n, 4, 128, 128);
    wt(Wip_self,  wt_ips, 1, 32, 128);
    wt(Wip_neigh, wt_ipn, 1, 32, 128);
    wt(W1_self,  wt_w1s, 5, 128, 128);
    wt(W1_neigh, wt_w1n, 5, 128, 128);
    wt(attnlin_W, wt_attn, 1, 128, 128);
    wt(fc_W, wt_fc, 1, 256, 128);

    k_lstm<<<dim3(N_ / 16, 2), dim3(512), 0, stream>>>(xtab, inp_s, inp_sm, Whh_f, Whh_b, hcat);

    // vec_url = lrelu(hcat @ fc_lstm_W + b) -> F0 cols [0,128)
    k_gemm<1, 0><<<dim3((N_ + 63) / 64, 1), dim3(256), 0, stream>>>(
        hcat, 256, 0, nullptr, 0, 0, wt_fclstm, 0, nullptr, 0,
        fc_lstm_b, 0, F0, 544, 0, N_, 256);
    k_pack<<<dim3(N_), dim3(128), 0, stream>>>(inp_c, inp_co, inp_sl, inp_ip,
                                               emb_cat, emb_cou, emb_sl, F0);

    // --- SAGE layer 0 ---
    k_agg<<<dim3(N_ / 4), dim3(256), 0, stream>>>(F0, 544, rowptr, colsrc, NEI, N_);
    // 4 embedding streams in one dispatch (blockIdx.y = stream)
    k_gemm<1, 1><<<dim3((N_ + 63) / 64, 4), dim3(256), 0, stream>>>(
        F0, 544, 128, NEI, 544, 128, wt_w0s, 128 * 128, wt_w0n, 128 * 128,
        b0, 128, F1, 640, 128, N_, 128);
    k_gemm<1, 1><<<dim3((N_ + 63) / 64, 1), dim3(256), 0, stream>>>(
        F0 + 512, 544, 0, NEI + 512, 544, 0, wt_ips, 0, wt_ipn, 0,
        bip, 0, F1 + 4 * 128, 640, 0, N_, 32);

    // --- SAGE layer 1 ---
    k_agg<<<dim3(N_ / 4), dim3(256), 0, stream>>>(F1, 640, rowptr, colsrc, NEI, N_);
    k_gemm<1, 1><<<dim3((N_ + 63) / 64, 5), dim3(256), 0, stream>>>(
        F1, 640, 128, NEI, 640, 128, wt_w1s, 128 * 128, wt_w1n, 128 * 128,
        b1, 128, H1, 640, 128, N_, 128);

    // --- attention ---
    // z: [N*5,128] = H1 @ attnlin_W  (H1 rows are exactly (n,s) pairs)
    k_gemm<0, 0><<<dim3((N_ * 5 + 63) / 64, 1), dim3(256), 0, stream>>>(
        H1, 128, 0, nullptr, 0, 0, wt_attn, 0, nullptr, 0,
        nullptr, 0, Zb, 128, 0, N_ * 5, 128);
    k_attn<<<dim3(N_ / 4), dim3(256), 0, stream>>>(Zb, attn_W, aA, hT, N_);

    // --- edge scoring ---
    k_edge<<<dim3(E2_ / 64), dim3(256), 0, stream>>>(hT, e_src, e_dst, wt_fc, fc_b,
                                                     fco_W, fco_b, out_score, E2_);
    k_attne<<<dim3(E2_ / 256), dim3(256), 0, stream>>>(aA, e_src, out_attne, E2_);
}

// Round 4
// 647.392 us; speedup vs baseline: 1.0909x; 1.0909x over previous
//
#include <hip/hip_runtime.h>
#include <hip/hip_bf16.h>
#include <stdint.h>

typedef unsigned short u16;
typedef unsigned int   u32;
typedef __attribute__((ext_vector_type(8))) short short8;   // 8 bf16 = MFMA A/B frag
typedef __attribute__((ext_vector_type(4))) float f32x4;    // MFMA C/D frag
typedef __attribute__((ext_vector_type(2))) u32   u32x2;
typedef __attribute__((ext_vector_type(4))) u32   u32x4;

#define DEV static __device__ __forceinline__

constexpr int N_  = 10000;
constexpr int T_  = 32;
constexpr int E_  = 320000;
constexpr int E2_ = 160000;

DEV u16 f2bf(float f) {
    union { float f; u32 u; } v; v.f = f;
    u32 u = v.u;
    return (u16)((u + 0x7fffu + ((u >> 16) & 1u)) >> 16);   // RNE
}
DEV float bf2f(u16 h) {
    union { u32 u; float f; } v; v.u = ((u32)h) << 16; return v.f;
}
DEV float asf(u32 u) {
    union { u32 u; float f; } v; v.u = u; return v.f;
}
DEV u32 cvt_pk_bf16(float lo, float hi) {
    u32 r;
    asm("v_cvt_pk_bf16_f32 %0, %1, %2" : "=v"(r) : "v"(lo), "v"(hi));
    return r;
}
DEV float lrelu(float x) { return x > 0.f ? x : 0.01f * x; }

DEV float fexp2(float x) {
#if __has_builtin(__builtin_amdgcn_exp2f)
    return __builtin_amdgcn_exp2f(x);
#else
    return exp2f(x);
#endif
}
DEV float frcp(float x) {
#if __has_builtin(__builtin_amdgcn_rcpf)
    return __builtin_amdgcn_rcpf(x);
#else
    return 1.0f / x;
#endif
}
DEV float fsig(float x)  { return frcp(1.f + fexp2(-1.4426950408889634f * x)); }
DEV float ftanh_(float x){ return 1.f - 2.f * frcp(1.f + fexp2(2.8853900817779268f * x)); }

// ---------------------------------------------------------------------------
// xtab[dir][sym][512] = emb_url[sym] @ Wih.T + b   (bf16)
// ---------------------------------------------------------------------------
__global__ void k_xtab(const float* __restrict__ emb,
                       const float* __restrict__ WihF, const float* __restrict__ bF,
                       const float* __restrict__ WihB, const float* __restrict__ bB,
                       u16* __restrict__ xtab) {
    int sym = blockIdx.x, dir = blockIdx.y, o = threadIdx.x;   // block 512
    const float* W = dir ? WihB : WihF;
    const float* b = dir ? bB : bF;
    __shared__ float er[128];
    if (o < 128) er[o] = emb[sym * 128 + o];
    __syncthreads();
    float s = b[o];
    for (int k = 0; k < 128; k++) s += er[k] * W[o * 128 + k];
    xtab[((size_t)(dir * 128 + sym)) * 512 + o] = f2bf(s);
}

// ---------------------------------------------------------------------------
// Merged weight transpose+convert: 9 segments in one dispatch.
// seg: W fp32 [S][K][Nw] -> out bf16 [S][Nw][K]
// ---------------------------------------------------------------------------
struct WtSeg { const float* W; u16* out; int K, Nw, tot; };
struct WtArgs { WtSeg seg[9]; };
__global__ void k_wt_all(WtArgs a) {
    WtSeg sg = a.seg[blockIdx.y];
    int i = blockIdx.x * 256 + threadIdx.x;
    if (i >= sg.tot) return;
    int K = sg.K, Nw = sg.Nw;
    int k = i % K, n = (i / K) % Nw, s = i / (K * Nw);
    sg.out[i] = f2bf(sg.W[((size_t)s * K + k) * Nw + n]);
}

// ---------------------------------------------------------------------------
// Bi-LSTM: block = 512 threads (8 waves) x 16 sequences, one direction.
// Wave w owns hidden units [16w,16w+16) for all 4 gates (64 VGPR of Whh).
// h in LDS in MFMA-fragment-major layout, double-buffered; one barrier/step.
// This round: xtab loads pipelined one step ahead; gate unpack via 1-op
// bit extracts; h packing via v_cvt_pk_bf16_f32; mask blend via cndmask.
// ---------------------------------------------------------------------------
__global__ __launch_bounds__(512, 2) void k_lstm(
    const u16* __restrict__ xtab,      // [2][128][512] bf16 (bias folded)
    const int* __restrict__ syms,      // [N][32]
    const int* __restrict__ smask,     // [N][32]
    const float* __restrict__ WhhF,    // [512][128]
    const float* __restrict__ WhhB,
    u16* __restrict__ hcat)            // [N][256] bf16 (fwd | bwd)
{
    __shared__ u16 h_buf[2][2048];     // [16 slabs][16 seq][8 elems]
    __shared__ int sym_l[512];         // [t][seq]
    __shared__ int msk_l[512];         // [t][seq]

    int tid = threadIdx.x;
    int w = tid >> 6, l = tid & 63, l15 = l & 15, lg = l >> 4;
    int dir = blockIdx.y;
    int n0 = blockIdx.x * 16;
    const float* Whh = dir ? WhhB : WhhF;

    for (int i = tid; i < 512; i += 512) {
        int seq = i >> 5, t = i & 31;
        sym_l[t * 16 + seq] = syms[(size_t)n0 * 32 + i];
        msk_l[t * 16 + seq] = smask[(size_t)n0 * 32 + i];
    }
    for (int i = tid; i < 2048; i += 512) h_buf[0][i] = 0;

    // A fragments: wave w covers gate gg, units 128*gg + 16*w + row
    short8 aw[4][4];
#pragma unroll
    for (int gg = 0; gg < 4; gg++)
#pragma unroll
    for (int kk = 0; kk < 4; kk++) {
        const float* p = Whh + (size_t)(128 * gg + 16 * w + l15) * 128 + 32 * kk + 8 * lg;
        const float4* pp = (const float4*)p;
        float4 x0 = pp[0], x1 = pp[1];
        short8 v;
        v[0] = (short)f2bf(x0.x); v[1] = (short)f2bf(x0.y);
        v[2] = (short)f2bf(x0.z); v[3] = (short)f2bf(x0.w);
        v[4] = (short)f2bf(x1.x); v[5] = (short)f2bf(x1.y);
        v[6] = (short)f2bf(x1.z); v[7] = (short)f2bf(x1.w);
        aw[gg][kk] = v;
    }

    float hreg[4] = {0, 0, 0, 0};
    float creg[4] = {0, 0, 0, 0};
    int jb = 16 * w + 4 * lg;          // hidden-unit base for this lane
    int wsk = 2 * w + (lg >> 1);       // write slab index (= jb>>3)
    int wof = (wsk * 16 + l15) * 8 + 4 * (lg & 1);
    const u16* xbase = xtab + (size_t)dir * 128 * 512 + jb;
    __syncthreads();

    // prologue: prefetch xtab gate inputs for step 0
    u32x2 xt[4];
    {
        int t0 = dir ? 31 : 0;
        int sym0 = sym_l[t0 * 16 + l15];
        const u16* xr = xbase + (size_t)sym0 * 512;
#pragma unroll
        for (int gg = 0; gg < 4; gg++) xt[gg] = *(const u32x2*)(xr + gg * 128);
    }

    for (int st = 0; st < 32; st++) {
        const u16* rb = h_buf[st & 1];
        u16* wb = h_buf[(st & 1) ^ 1];
        int t = dir ? (31 - st) : st;
        int mt_i = msk_l[t * 16 + l15];

        // prefetch next step's xtab inputs (latency hidden under MFMA+VALU)
        u32x2 xtn[4];
        {
            int stn = (st < 31) ? (st + 1) : 31;
            int tn = dir ? (31 - stn) : stn;
            int symn = sym_l[tn * 16 + l15];
            const u16* xr = xbase + (size_t)symn * 512;
#pragma unroll
            for (int gg = 0; gg < 4; gg++) xtn[gg] = *(const u32x2*)(xr + gg * 128);
        }

        // B fragments: contiguous 1KB slab per wave, conflict-free
        short8 bh[4];
#pragma unroll
        for (int kk = 0; kk < 4; kk++)
            bh[kk] = *(const short8*)&rb[((kk * 4 + lg) * 16 + l15) * 8];

        f32x4 acc[4];
#pragma unroll
        for (int gg = 0; gg < 4; gg++) {
            f32x4 a = {0.f, 0.f, 0.f, 0.f};
#pragma unroll
            for (int kk = 0; kk < 4; kk++)
                a = __builtin_amdgcn_mfma_f32_16x16x32_bf16(aw[gg][kk], bh[kk], a, 0, 0, 0);
            acc[gg] = a;
        }

        bool mb = mt_i != 0;
        float hN[4];
#pragma unroll
        for (int r = 0; r < 4; r++) {
            // compile-time word/half selection -> 1 bit-op per gate extract
            u32 wi = xt[0][r >> 1], wf = xt[1][r >> 1], wg = xt[2][r >> 1], wo = xt[3][r >> 1];
            float xi, xf, xg, xo;
            if (r & 1) {
                xi = asf(wi & 0xffff0000u); xf = asf(wf & 0xffff0000u);
                xg = asf(wg & 0xffff0000u); xo = asf(wo & 0xffff0000u);
            } else {
                xi = asf(wi << 16); xf = asf(wf << 16);
                xg = asf(wg << 16); xo = asf(wo << 16);
            }
            float gi = acc[0][r] + xi;
            float gf = acc[1][r] + xf;
            float gc = acc[2][r] + xg;
            float go = acc[3][r] + xo;
            float i_ = fsig(gi), f_ = fsig(gf), g_ = ftanh_(gc), o_ = fsig(go);
            float cn = f_ * creg[r] + i_ * g_;
            float hn = o_ * ftanh_(cn);
            hN[r]   = mb ? hn : hreg[r];
            creg[r] = mb ? cn : creg[r];
            hreg[r] = hN[r];
        }
        u32x2 pk;
        pk[0] = cvt_pk_bf16(hN[0], hN[1]);
        pk[1] = cvt_pk_bf16(hN[2], hN[3]);
        *(u32x2*)&wb[wof] = pk;
#pragma unroll
        for (int gg = 0; gg < 4; gg++) xt[gg] = xtn[gg];
        __syncthreads();   // writes to wb visible before next step reads it
    }

    // final hidden -> hcat[n][dir*128 + j]
    {
        u32x2 pk;
        pk[0] = cvt_pk_bf16(hreg[0], hreg[1]);
        pk[1] = cvt_pk_bf16(hreg[2], hreg[3]);
        *(u32x2*)&hcat[(size_t)(n0 + l15) * 256 + dir * 128 + jb] = pk;
    }
}

// ---------------------------------------------------------------------------
// Generic MFMA GEMM: C[M,128] = act(A1@B1 [+ A2@B2] + bias), bf16 in/out.
// B pre-transposed bf16 [128][K]. Block = 4 waves x 16 rows.
// blockIdx.y = stream index s; so* are per-stream element offsets.
// ---------------------------------------------------------------------------
template<int ACT, int DUAL>
__global__ __launch_bounds__(256) void k_gemm(
    const u16* __restrict__ A1, int lda1, int soA1,
    const u16* __restrict__ A2, int lda2, int soA2,
    const u16* __restrict__ B1, int soB1,
    const u16* __restrict__ B2, int soB2,
    const float* __restrict__ bias, int soBias,
    u16* __restrict__ C, int ldc, int soC, int M, int K)
{
    int s = blockIdx.y;
    A1 += (size_t)s * soA1;
    if (DUAL) A2 += (size_t)s * soA2;
    B1 += (size_t)s * soB1;
    if (DUAL) B2 += (size_t)s * soB2;
    if (bias) bias += (size_t)s * soBias;
    C += (size_t)s * soC;

    int tid = threadIdx.x;
    int w = tid >> 6, l = tid & 63, l15 = l & 15, lg = l >> 4;
    int mbase = blockIdx.x * 64 + w * 16;
    int arow = mbase + l15; if (arow >= M) arow = M - 1;

    f32x4 acc[8];
#pragma unroll
    for (int nt = 0; nt < 8; nt++) {
        float bv = bias ? bias[16 * nt + l15] : 0.f;
        acc[nt] = (f32x4){bv, bv, bv, bv};
    }
    for (int k0 = 0; k0 < K; k0 += 32) {
        int k = k0 + 8 * lg;
        short8 a1 = *(const short8*)&A1[(size_t)arow * lda1 + k];
        short8 a2;
        if (DUAL) a2 = *(const short8*)&A2[(size_t)arow * lda2 + k];
#pragma unroll
        for (int nt = 0; nt < 8; nt++) {
            short8 b1 = *(const short8*)&B1[(size_t)(16 * nt + l15) * K + k];
            acc[nt] = __builtin_amdgcn_mfma_f32_16x16x32_bf16(a1, b1, acc[nt], 0, 0, 0);
            if (DUAL) {
                short8 b2 = *(const short8*)&B2[(size_t)(16 * nt + l15) * K + k];
                acc[nt] = __builtin_amdgcn_mfma_f32_16x16x32_bf16(a2, b2, acc[nt], 0, 0, 0);
            }
        }
    }
#pragma unroll
    for (int nt = 0; nt < 8; nt++)
#pragma unroll
    for (int r = 0; r < 4; r++) {
        int m = mbase + 4 * lg + r;
        if (m < M) {
            float v = acc[nt][r];
            if (ACT == 1) v = lrelu(v);
            C[(size_t)m * ldc + 16 * nt + l15] = f2bf(v);
        }
    }
}

// ---------------------------------------------------------------------------
// F0 packing: embedding gathers + ip  (cols 128..543; cols 0..127 by gemm)
// ---------------------------------------------------------------------------
__global__ void k_pack(const int* __restrict__ ic, const int* __restrict__ ico,
                       const int* __restrict__ isl, const float* __restrict__ ip,
                       const float* __restrict__ ecat, const float* __restrict__ ecou,
                       const float* __restrict__ esl, u16* __restrict__ F0) {
    int n = blockIdx.x, t = threadIdx.x;   // block 128
    u16* row = F0 + (size_t)n * 544;
    row[128 + t] = f2bf(ecat[(size_t)ic[n]  * 128 + t]);
    row[256 + t] = f2bf(ecou[(size_t)ico[n] * 128 + t]);
    row[384 + t] = f2bf(esl [(size_t)isl[n] * 128 + t]);
    if (t < 32) row[512 + t] = f2bf(ip[(size_t)n * 32 + t]);
}

// ---------------------------------------------------------------------------
// CSR build
// ---------------------------------------------------------------------------
__global__ void k_hist(const int* __restrict__ dst, int E, int* __restrict__ deg) {
    int e = blockIdx.x * 256 + threadIdx.x;
    if (e < E) atomicAdd(&deg[dst[e]], 1);
}
__global__ void k_scan(const int* __restrict__ deg, int* __restrict__ rowptr,
                       int* __restrict__ cursor, int n) {
    __shared__ int part[1024];
    int tid = threadIdx.x;
    const int CH = 10;
    int base = tid * CH;
    int s = 0;
#pragma unroll
    for (int i = 0; i < CH; i++) { int idx = base + i; if (idx < n) s += deg[idx]; }
    part[tid] = s; __syncthreads();
    for (int off = 1; off < 1024; off <<= 1) {
        int v = (tid >= off) ? part[tid - off] : 0;
        __syncthreads();
        part[tid] += v;
        __syncthreads();
    }
    int run = part[tid] - s;
    for (int i = 0; i < CH; i++) {
        int idx = base + i;
        if (idx < n) { rowptr[idx] = run; cursor[idx] = run; run += deg[idx]; }
    }
    if (tid == 1023) rowptr[n] = part[1023];
}
__global__ void k_fill(const int* __restrict__ src, const int* __restrict__ dst, int E,
                       int* __restrict__ cursor, int* __restrict__ colsrc) {
    int e = blockIdx.x * 256 + threadIdx.x;
    if (e < E) {
        int pos = atomicAdd(&cursor[dst[e]], 1);
        colsrc[pos] = src[e];
    }
}

// ---------------------------------------------------------------------------
// Mean aggregation: wave per node, uint4-chunked bf16 rows.
// ---------------------------------------------------------------------------
__global__ __launch_bounds__(256) void k_agg(const u16* __restrict__ F, int C,
                                             const int* __restrict__ rowptr,
                                             const int* __restrict__ colsrc,
                                             u16* __restrict__ out, int N) {
    int w = threadIdx.x >> 6, l = threadIdx.x & 63;
    int n = blockIdx.x * 4 + w;
    if (n >= N) return;
    int chunks = C >> 3;
    int c0 = l, c1 = l + 64;
    bool has1 = c1 < chunks;
    float a0[8] = {0,0,0,0,0,0,0,0}, a1[8] = {0,0,0,0,0,0,0,0};
    int beg = rowptr[n], end = rowptr[n + 1];
    for (int e = beg; e < end; e++) {
        int s = colsrc[e];
        const u32x4* rp = (const u32x4*)(F + (size_t)s * C);
        u32x4 v0 = rp[c0];
#pragma unroll
        for (int j = 0; j < 4; j++) {
            u32 u = v0[j];
            a0[2*j]   += bf2f((u16)u);
            a0[2*j+1] += bf2f((u16)(u >> 16));
        }
        if (has1) {
            u32x4 v1 = rp[c1];
#pragma unroll
            for (int j = 0; j < 4; j++) {
                u32 u = v1[j];
                a1[2*j]   += bf2f((u16)u);
                a1[2*j+1] += bf2f((u16)(u >> 16));
            }
        }
    }
    int dg = end - beg; if (dg < 1) dg = 1;
    float inv = 1.f / (float)dg;
    u32x4 o0;
#pragma unroll
    for (int j = 0; j < 4; j++)
        o0[j] = (u32)f2bf(a0[2*j] * inv) | ((u32)f2bf(a0[2*j+1] * inv) << 16);
    ((u32x4*)(out + (size_t)n * C))[c0] = o0;
    if (has1) {
        u32x4 o1;
#pragma unroll
        for (int j = 0; j < 4; j++)
            o1[j] = (u32)f2bf(a1[2*j] * inv) | ((u32)f2bf(a1[2*j+1] * inv) << 16);
        ((u32x4*)(out + (size_t)n * C))[c1] = o1;
    }
}

// ---------------------------------------------------------------------------
// Attention fusion: wave per node. logits -> softmax(5) -> a, h = sum a*z.
// (attn_b is a constant shift -> softmax-invariant, skipped.)
// ---------------------------------------------------------------------------
__global__ __launch_bounds__(256) void k_attn(const u16* __restrict__ Z,
                                              const float* __restrict__ attnW,
                                              float* __restrict__ aOut,
                                              u16* __restrict__ hT, int N) {
    int w = threadIdx.x >> 6, l = threadIdx.x & 63;
    int n = blockIdx.x * 4 + w;
    if (n >= N) return;
    float wa0 = attnW[l], wa1 = attnW[l + 64];
    float z0[5], z1[5], lgt[5];
#pragma unroll
    for (int s = 0; s < 5; s++) {
        z0[s] = bf2f(Z[((size_t)(n * 5 + s)) * 128 + l]);
        z1[s] = bf2f(Z[((size_t)(n * 5 + s)) * 128 + l + 64]);
        float p = z0[s] * wa0 + z1[s] * wa1;
#pragma unroll
        for (int m = 1; m < 64; m <<= 1) p += __shfl_xor(p, m, 64);
        lgt[s] = p;
    }
    float mx = lgt[0];
#pragma unroll
    for (int s = 1; s < 5; s++) mx = fmaxf(mx, lgt[s]);
    float ex[5], sum = 0.f;
#pragma unroll
    for (int s = 0; s < 5; s++) { ex[s] = __expf(lgt[s] - mx); sum += ex[s]; }
    float a[5];
#pragma unroll
    for (int s = 0; s < 5; s++) a[s] = ex[s] / sum;
    float h0 = 0.f, h1 = 0.f;
#pragma unroll
    for (int s = 0; s < 5; s++) { h0 += a[s] * z0[s]; h1 += a[s] * z1[s]; }
    hT[(size_t)n * 128 + l] = f2bf(h0);
    hT[(size_t)n * 128 + l + 64] = f2bf(h1);
    if (l == 0) {
#pragma unroll
        for (int s = 0; s < 5; s++) aOut[(size_t)n * 5 + s] = a[s];
    }
}

// ---------------------------------------------------------------------------
// Edge MLP fused: score = lrelu([h_src|h_dst]@fcW + fcb)@fcoW + fcob
// wave per 16 edges; second matmul as in-register shfl reduce.
// ---------------------------------------------------------------------------
__global__ __launch_bounds__(256) void k_edge(const u16* __restrict__ hT,
                                              const int* __restrict__ esrc,
                                              const int* __restrict__ edst,
                                              const u16* __restrict__ fcWt,  // [128][256]
                                              const float* __restrict__ fcb,
                                              const float* __restrict__ fcoW, // [128][2]
                                              const float* __restrict__ fcob,
                                              float* __restrict__ score, int E2) {
    int tid = threadIdx.x;
    int w = tid >> 6, l = tid & 63, l15 = l & 15, lg = l >> 4;
    int eb = (blockIdx.x * 4 + w) * 16;
    int arow = eb + l15; if (arow >= E2) arow = E2 - 1;
    int sn = esrc[arow], dn = edst[arow];

    f32x4 acc[8];
#pragma unroll
    for (int nt = 0; nt < 8; nt++) {
        float bv = fcb[16 * nt + l15];
        acc[nt] = (f32x4){bv, bv, bv, bv};
    }
#pragma unroll
    for (int kk = 0; kk < 8; kk++) {
        int k = 32 * kk + 8 * lg;
        const u16* ap = (k < 128) ? &hT[(size_t)sn * 128 + k]
                                  : &hT[(size_t)dn * 128 + (k - 128)];
        short8 a = *(const short8*)ap;
#pragma unroll
        for (int nt = 0; nt < 8; nt++) {
            short8 b = *(const short8*)&fcWt[(size_t)(16 * nt + l15) * 256 + k];
            acc[nt] = __builtin_amdgcn_mfma_f32_16x16x32_bf16(a, b, acc[nt], 0, 0, 0);
        }
    }
    float p0[4] = {0,0,0,0}, p1[4] = {0,0,0,0};
#pragma unroll
    for (int nt = 0; nt < 8; nt++) {
        int c = 16 * nt + l15;
        float w0 = fcoW[c * 2], w1 = fcoW[c * 2 + 1];
#pragma unroll
        for (int r = 0; r < 4; r++) {
            float hd = lrelu(acc[nt][r]);
            p0[r] += hd * w0; p1[r] += hd * w1;
        }
    }
#pragma unroll
    for (int m = 1; m < 16; m <<= 1) {
#pragma unroll
        for (int r = 0; r < 4; r++) {
            p0[r] += __shfl_xor(p0[r], m, 64);
            p1[r] += __shfl_xor(p1[r], m, 64);
        }
    }
    if (l15 == 0) {
        float b0v = fcob[0], b1v = fcob[1];
#pragma unroll
        for (int r = 0; r < 4; r++) {
            int e = eb + 4 * lg + r;
            if (e < E2) {
                score[(size_t)e * 2 + 0] = p0[r] + b0v;
                score[(size_t)e * 2 + 1] = p1[r] + b1v;
            }
        }
    }
}

// ---------------------------------------------------------------------------
// attn_e output: [E2,2,5] both rows = a[e_src]
// ---------------------------------------------------------------------------
__global__ void k_attne(const float* __restrict__ a, const int* __restrict__ esrc,
                        float* __restrict__ out, int E2) {
    int m = blockIdx.x * 256 + threadIdx.x;
    if (m >= E2) return;
    int s = esrc[m];
#pragma unroll
    for (int i = 0; i < 5; i++) {
        float v = a[(size_t)s * 5 + i];
        out[(size_t)m * 10 + i] = v;
        out[(size_t)m * 10 + 5 + i] = v;
    }
}

// ---------------------------------------------------------------------------
extern "C" void kernel_launch(void* const* d_in, const int* in_sizes, int n_in,
                              void* d_out, int out_size, void* d_ws, size_t ws_size,
                              hipStream_t stream) {
    const int* inp_s   = (const int*)d_in[0];
    const int* inp_sm  = (const int*)d_in[1];
    const int* inp_c   = (const int*)d_in[2];
    const int* inp_co  = (const int*)d_in[3];
    const int* inp_sl  = (const int*)d_in[4];
    const float* inp_ip = (const float*)d_in[5];
    const int* blk_src = (const int*)d_in[6];
    const int* blk_dst = (const int*)d_in[7];
    const int* e_src   = (const int*)d_in[8];
    const int* e_dst   = (const int*)d_in[9];
    const float* emb_url = (const float*)d_in[10];
    const float* emb_cat = (const float*)d_in[11];
    const float* emb_cou = (const float*)d_in[12];
    const float* emb_sl  = (const float*)d_in[13];
    const float* Wih_f = (const float*)d_in[14];
    const float* Whh_f = (const float*)d_in[15];
    const float* b_f   = (const float*)d_in[16];
    const float* Wih_b = (const float*)d_in[17];
    const float* Whh_b = (const float*)d_in[18];
    const float* b_b   = (const float*)d_in[19];
    const float* fc_lstm_W = (const float*)d_in[20];
    const float* fc_lstm_b = (const float*)d_in[21];
    const float* attnlin_W = (const float*)d_in[22];
    const float* attn_W    = (const float*)d_in[23];
    /* d_in[24] attn_b: softmax shift-invariant, unused */
    const float* W0_self  = (const float*)d_in[25];
    const float* W0_neigh = (const float*)d_in[26];
    const float* b0       = (const float*)d_in[27];
    const float* Wip_self  = (const float*)d_in[28];
    const float* Wip_neigh = (const float*)d_in[29];
    const float* bip       = (const float*)d_in[30];
    const float* W1_self  = (const float*)d_in[31];
    const float* W1_neigh = (const float*)d_in[32];
    const float* b1       = (const float*)d_in[33];
    const float* fc_W  = (const float*)d_in[34];
    const float* fc_b  = (const float*)d_in[35];
    const float* fco_W = (const float*)d_in[36];
    const float* fco_b = (const float*)d_in[37];

    char* ws = (char*)d_ws;
    size_t off = 0;
    auto alloc = [&](size_t bytes) -> char* {
        char* p = ws + off;
        off += (bytes + 255) & ~(size_t)255;
        return p;
    };
    u16* xtab      = (u16*)alloc((size_t)2 * 128 * 512 * 2);
    u16* hcat      = (u16*)alloc((size_t)N_ * 256 * 2);
    u16* wt_fclstm = (u16*)alloc((size_t)128 * 256 * 2);
    u16* wt_w0s    = (u16*)alloc((size_t)4 * 128 * 128 * 2);
    u16* wt_w0n    = (u16*)alloc((size_t)4 * 128 * 128 * 2);
    u16* wt_ips    = (u16*)alloc((size_t)128 * 32 * 2);
    u16* wt_ipn    = (u16*)alloc((size_t)128 * 32 * 2);
    u16* wt_w1s    = (u16*)alloc((size_t)5 * 128 * 128 * 2);
    u16* wt_w1n    = (u16*)alloc((size_t)5 * 128 * 128 * 2);
    u16* wt_attn   = (u16*)alloc((size_t)128 * 128 * 2);
    u16* wt_fc     = (u16*)alloc((size_t)128 * 256 * 2);
    u16* F0        = (u16*)alloc((size_t)N_ * 544 * 2);
    u16* NEI       = (u16*)alloc((size_t)N_ * 640 * 2);
    u16* F1        = (u16*)alloc((size_t)N_ * 640 * 2);
    u16* H1        = (u16*)alloc((size_t)N_ * 640 * 2);
    u16* Zb        = (u16*)alloc((size_t)N_ * 5 * 128 * 2);
    u16* hT        = (u16*)alloc((size_t)N_ * 128 * 2);
    float* aA      = (float*)alloc((size_t)N_ * 5 * 4);
    int* deg       = (int*)alloc((size_t)N_ * 4);
    int* rowptr    = (int*)alloc((size_t)(N_ + 1) * 4);
    int* cursor    = (int*)alloc((size_t)N_ * 4);
    int* colsrc    = (int*)alloc((size_t)E_ * 4);
    (void)ws_size; (void)in_sizes; (void)n_in; (void)out_size;

    float* out_score = (float*)d_out;
    float* out_attne = out_score + (size_t)2 * E2_;

    // --- CSR build ---
    hipMemsetAsync(deg, 0, (size_t)N_ * 4, stream);
    k_hist<<<dim3((E_ + 255) / 256), dim3(256), 0, stream>>>(blk_dst, E_, deg);
    k_scan<<<dim3(1), dim3(1024), 0, stream>>>(deg, rowptr, cursor, N_);
    k_fill<<<dim3((E_ + 255) / 256), dim3(256), 0, stream>>>(blk_src, blk_dst, E_, cursor, colsrc);

    // --- LSTM prep + run ---
    k_xtab<<<dim3(128, 2), dim3(512), 0, stream>>>(emb_url, Wih_f, b_f, Wih_b, b_b, xtab);
    {
        WtArgs a;
        a.seg[0] = {fc_lstm_W, wt_fclstm, 256, 128, 1 * 128 * 256};
        a.seg[1] = {W0_self,   wt_w0s,    128, 128, 4 * 128 * 128};
        a.seg[2] = {W0_neigh,  wt_w0n,    128, 128, 4 * 128 * 128};
        a.seg[3] = {Wip_self,  wt_ips,     32, 128, 1 * 128 * 32};
        a.seg[4] = {Wip_neigh, wt_ipn,     32, 128, 1 * 128 * 32};
        a.seg[5] = {W1_self,   wt_w1s,    128, 128, 5 * 128 * 128};
        a.seg[6] = {W1_neigh,  wt_w1n,    128, 128, 5 * 128 * 128};
        a.seg[7] = {attnlin_W, wt_attn,   128, 128, 1 * 128 * 128};
        a.seg[8] = {fc_W,      wt_fc,     256, 128, 1 * 128 * 256};
        k_wt_all<<<dim3((5 * 128 * 128 + 255) / 256, 9), dim3(256), 0, stream>>>(a);
    }

    k_lstm<<<dim3(N_ / 16, 2), dim3(512), 0, stream>>>(xtab, inp_s, inp_sm, Whh_f, Whh_b, hcat);

    // vec_url = lrelu(hcat @ fc_lstm_W + b) -> F0 cols [0,128)
    k_gemm<1, 0><<<dim3((N_ + 63) / 64, 1), dim3(256), 0, stream>>>(
        hcat, 256, 0, nullptr, 0, 0, wt_fclstm, 0, nullptr, 0,
        fc_lstm_b, 0, F0, 544, 0, N_, 256);
    k_pack<<<dim3(N_), dim3(128), 0, stream>>>(inp_c, inp_co, inp_sl, inp_ip,
                                               emb_cat, emb_cou, emb_sl, F0);

    // --- SAGE layer 0 ---
    k_agg<<<dim3(N_ / 4), dim3(256), 0, stream>>>(F0, 544, rowptr, colsrc, NEI, N_);
    // 4 embedding streams in one dispatch (blockIdx.y = stream)
    k_gemm<1, 1><<<dim3((N_ + 63) / 64, 4), dim3(256), 0, stream>>>(
        F0, 544, 128, NEI, 544, 128, wt_w0s, 128 * 128, wt_w0n, 128 * 128,
        b0, 128, F1, 640, 128, N_, 128);
    k_gemm<1, 1><<<dim3((N_ + 63) / 64, 1), dim3(256), 0, stream>>>(
        F0 + 512, 544, 0, NEI + 512, 544, 0, wt_ips, 0, wt_ipn, 0,
        bip, 0, F1 + 4 * 128, 640, 0, N_, 32);

    // --- SAGE layer 1 ---
    k_agg<<<dim3(N_ / 4), dim3(256), 0, stream>>>(F1, 640, rowptr, colsrc, NEI, N_);
    k_gemm<1, 1><<<dim3((N_ + 63) / 64, 5), dim3(256), 0, stream>>>(
        F1, 640, 128, NEI, 640, 128, wt_w1s, 128 * 128, wt_w1n, 128 * 128,
        b1, 128, H1, 640, 128, N_, 128);

    // --- attention ---
    // z: [N*5,128] = H1 @ attnlin_W  (H1 rows are exactly (n,s) pairs)
    k_gemm<0, 0><<<dim3((N_ * 5 + 63) / 64, 1), dim3(256), 0, stream>>>(
        H1, 128, 0, nullptr, 0, 0, wt_attn, 0, nullptr, 0,
        nullptr, 0, Zb, 128, 0, N_ * 5, 128);
    k_attn<<<dim3(N_ / 4), dim3(256), 0, stream>>>(Zb, attn_W, aA, hT, N_);

    // --- edge scoring ---
    k_edge<<<dim3(E2_ / 64), dim3(256), 0, stream>>>(hT, e_src, e_dst, wt_fc, fc_b,
                                                     fco_W, fco_b, out_score, E2_);
    k_attne<<<dim3(E2_ / 256), dim3(256), 0, stream>>>(aA, e_src, out_attne, E2_);
}

// Round 5
// 597.410 us; speedup vs baseline: 1.1821x; 1.0837x over previous
//
#include <hip/hip_runtime.h>
#include <hip/hip_bf16.h>
#include <stdint.h>

typedef unsigned short u16;
typedef unsigned int   u32;
typedef __attribute__((ext_vector_type(8))) short short8;   // 8 bf16 = MFMA A/B frag
typedef __attribute__((ext_vector_type(4))) float f32x4;    // MFMA C/D frag
typedef __attribute__((ext_vector_type(2))) u32   u32x2;
typedef __attribute__((ext_vector_type(4))) u32   u32x4;

#define DEV static __device__ __forceinline__

constexpr int N_  = 10000;
constexpr int T_  = 32;
constexpr int E_  = 320000;
constexpr int E2_ = 160000;

DEV u16 f2bf(float f) {
    union { float f; u32 u; } v; v.f = f;
    u32 u = v.u;
    return (u16)((u + 0x7fffu + ((u >> 16) & 1u)) >> 16);   // RNE
}
DEV float bf2f(u16 h) {
    union { u32 u; float f; } v; v.u = ((u32)h) << 16; return v.f;
}
DEV float asf(u32 u) {
    union { u32 u; float f; } v; v.u = u; return v.f;
}
DEV u32 cvt_pk_bf16(float lo, float hi) {
    u32 r;
    asm("v_cvt_pk_bf16_f32 %0, %1, %2" : "=v"(r) : "v"(lo), "v"(hi));
    return r;
}
DEV float lrelu(float x) { return x > 0.f ? x : 0.01f * x; }

DEV float fexp2(float x) {
#if __has_builtin(__builtin_amdgcn_exp2f)
    return __builtin_amdgcn_exp2f(x);
#else
    return exp2f(x);
#endif
}
DEV float frcp(float x) {
#if __has_builtin(__builtin_amdgcn_rcpf)
    return __builtin_amdgcn_rcpf(x);
#else
    return 1.0f / x;
#endif
}
DEV float fsig(float x)  { return frcp(1.f + fexp2(-1.4426950408889634f * x)); }
DEV float ftanh_(float x){ return 1.f - 2.f * frcp(1.f + fexp2(2.8853900817779268f * x)); }

// ---------------------------------------------------------------------------
// xtab[dir][sym][512] = emb_url[sym] @ Wih.T + b   (bf16)
// ---------------------------------------------------------------------------
__global__ void k_xtab(const float* __restrict__ emb,
                       const float* __restrict__ WihF, const float* __restrict__ bF,
                       const float* __restrict__ WihB, const float* __restrict__ bB,
                       u16* __restrict__ xtab) {
    int sym = blockIdx.x, dir = blockIdx.y, o = threadIdx.x;   // block 512
    const float* W = dir ? WihB : WihF;
    const float* b = dir ? bB : bF;
    __shared__ float er[128];
    if (o < 128) er[o] = emb[sym * 128 + o];
    __syncthreads();
    float s = b[o];
    for (int k = 0; k < 128; k++) s += er[k] * W[o * 128 + k];
    xtab[((size_t)(dir * 128 + sym)) * 512 + o] = f2bf(s);
}

// ---------------------------------------------------------------------------
// Merged weight transpose+convert (with K zero-padding for the ip stream):
// W fp32 [S][Ks][Nw] -> out bf16 [S][Nw][Kd], k>=Ks zero-filled.
// ---------------------------------------------------------------------------
struct WtSeg { const float* W; u16* out; int Kd, Ks, Nw, tot; };
struct WtArgs { WtSeg seg[9]; };
__global__ void k_wt_all(WtArgs a) {
    WtSeg sg = a.seg[blockIdx.y];
    int i = blockIdx.x * 256 + threadIdx.x;
    if (i >= sg.tot) return;
    int k = i % sg.Kd, n = (i / sg.Kd) % sg.Nw, s = i / (sg.Kd * sg.Nw);
    float v = (k < sg.Ks) ? sg.W[((size_t)s * sg.Ks + k) * sg.Nw + n] : 0.f;
    sg.out[i] = f2bf(v);
}

// ---------------------------------------------------------------------------
// Bi-LSTM: block = 512 threads (8 waves) x 16 sequences, one direction.
// Wave w owns hidden units [16w,16w+16) for all 4 gates (64 VGPR of Whh).
// h in LDS in MFMA-fragment-major layout, double-buffered; one barrier/step.
// This round: xtab gate inputs folded into MFMA acc INIT (saves the adds);
// manual 2-step unroll (compile-time LDS bases, no xt reg-copies).
// ---------------------------------------------------------------------------
__global__ __launch_bounds__(512, 2) void k_lstm(
    const u16* __restrict__ xtab,      // [2][128][512] bf16 (bias folded)
    const int* __restrict__ syms,      // [N][32]
    const int* __restrict__ smask,     // [N][32]
    const float* __restrict__ WhhF,    // [512][128]
    const float* __restrict__ WhhB,
    u16* __restrict__ hcat)            // [N][256] bf16 (fwd | bwd)
{
    __shared__ u16 h_buf0[2048];       // [16 slabs][16 seq][8 elems]
    __shared__ u16 h_buf1[2048];
    __shared__ int sym_l[512];         // [t][seq]
    __shared__ int msk_l[512];         // [t][seq]

    int tid = threadIdx.x;
    int w = tid >> 6, l = tid & 63, l15 = l & 15, lg = l >> 4;
    int dir = blockIdx.y;
    int n0 = blockIdx.x * 16;
    const float* Whh = dir ? WhhB : WhhF;

    for (int i = tid; i < 512; i += 512) {
        int seq = i >> 5, t = i & 31;
        sym_l[t * 16 + seq] = syms[(size_t)n0 * 32 + i];
        msk_l[t * 16 + seq] = smask[(size_t)n0 * 32 + i];
    }
    for (int i = tid; i < 2048; i += 512) h_buf0[i] = 0;

    // A fragments: wave w covers gate gg, units 128*gg + 16*w + row
    short8 aw[4][4];
#pragma unroll
    for (int gg = 0; gg < 4; gg++)
#pragma unroll
    for (int kk = 0; kk < 4; kk++) {
        const float* p = Whh + (size_t)(128 * gg + 16 * w + l15) * 128 + 32 * kk + 8 * lg;
        const float4* pp = (const float4*)p;
        float4 x0 = pp[0], x1 = pp[1];
        short8 v;
        v[0] = (short)f2bf(x0.x); v[1] = (short)f2bf(x0.y);
        v[2] = (short)f2bf(x0.z); v[3] = (short)f2bf(x0.w);
        v[4] = (short)f2bf(x1.x); v[5] = (short)f2bf(x1.y);
        v[6] = (short)f2bf(x1.z); v[7] = (short)f2bf(x1.w);
        aw[gg][kk] = v;
    }

    float hreg[4] = {0, 0, 0, 0};
    float creg[4] = {0, 0, 0, 0};
    int jb = 16 * w + 4 * lg;          // hidden-unit base for this lane
    int wsk = 2 * w + (lg >> 1);       // write slab index (= jb>>3)
    int wof = (wsk * 16 + l15) * 8 + 4 * (lg & 1);
    const u16* xbase = xtab + (size_t)dir * 128 * 512 + jb;
    __syncthreads();

    u32x2 xtA[4], xtB[4];
    {   // prologue: prefetch xtab gate inputs for step 0
        int t0 = dir ? 31 : 0;
        int sym0 = sym_l[t0 * 16 + l15];
        const u16* xr = xbase + (size_t)sym0 * 512;
#pragma unroll
        for (int gg = 0; gg < 4; gg++) xtA[gg] = *(const u32x2*)(xr + gg * 128);
    }

    auto step = [&](int st, const u16* rb, u16* wb, u32x2 (&xt)[4], u32x2 (&xtn)[4]) {
        int t = dir ? (31 - st) : st;
        int mt_i = msk_l[t * 16 + l15];

        // prefetch next step's xtab inputs (hidden under MFMA+VALU)
        int stn = (st < 31) ? (st + 1) : 31;
        int tn = dir ? (31 - stn) : stn;
        int symn = sym_l[tn * 16 + l15];
        const u16* xr = xbase + (size_t)symn * 512;
#pragma unroll
        for (int gg = 0; gg < 4; gg++) xtn[gg] = *(const u32x2*)(xr + gg * 128);

        // B fragments: contiguous 1KB slab per wave, conflict-free
        short8 bh[4];
#pragma unroll
        for (int kk = 0; kk < 4; kk++)
            bh[kk] = *(const short8*)&rb[((kk * 4 + lg) * 16 + l15) * 8];

        f32x4 acc[4];
#pragma unroll
        for (int gg = 0; gg < 4; gg++) {
            // init C with the xtab gate inputs (x@Wih.T + b), no post-add
            f32x4 a = { asf(xt[gg][0] << 16), asf(xt[gg][0] & 0xffff0000u),
                        asf(xt[gg][1] << 16), asf(xt[gg][1] & 0xffff0000u) };
#pragma unroll
            for (int kk = 0; kk < 4; kk++)
                a = __builtin_amdgcn_mfma_f32_16x16x32_bf16(aw[gg][kk], bh[kk], a, 0, 0, 0);
            acc[gg] = a;
        }

        bool mb = mt_i != 0;
        float hN[4];
#pragma unroll
        for (int r = 0; r < 4; r++) {
            float i_ = fsig(acc[0][r]), f_ = fsig(acc[1][r]);
            float g_ = ftanh_(acc[2][r]), o_ = fsig(acc[3][r]);
            float cn = f_ * creg[r] + i_ * g_;
            float hn = o_ * ftanh_(cn);
            hN[r]   = mb ? hn : hreg[r];
            creg[r] = mb ? cn : creg[r];
            hreg[r] = hN[r];
        }
        u32x2 pk;
        pk[0] = cvt_pk_bf16(hN[0], hN[1]);
        pk[1] = cvt_pk_bf16(hN[2], hN[3]);
        *(u32x2*)&wb[wof] = pk;
        __syncthreads();   // writes to wb visible before next step reads it
    };

    for (int st2 = 0; st2 < 16; st2++) {
        step(2 * st2,     h_buf0, h_buf1, xtA, xtB);
        step(2 * st2 + 1, h_buf1, h_buf0, xtB, xtA);
    }

    // final hidden -> hcat[n][dir*128 + j]
    {
        u32x2 pk;
        pk[0] = cvt_pk_bf16(hreg[0], hreg[1]);
        pk[1] = cvt_pk_bf16(hreg[2], hreg[3]);
        *(u32x2*)&hcat[(size_t)(n0 + l15) * 256 + dir * 128 + jb] = pk;
    }
}

// ---------------------------------------------------------------------------
// Generic MFMA GEMM: C[M,128] = act(A1@B1 [+ A2@B2] + bias), bf16 in/out.
// B pre-transposed bf16 [128][K]. Block = 4 waves x 16 rows.
// blockIdx.y = stream index s; so* are per-stream element offsets.
// ---------------------------------------------------------------------------
template<int ACT, int DUAL>
__global__ __launch_bounds__(256) void k_gemm(
    const u16* __restrict__ A1, int lda1, int soA1,
    const u16* __restrict__ A2, int lda2, int soA2,
    const u16* __restrict__ B1, int soB1,
    const u16* __restrict__ B2, int soB2,
    const float* __restrict__ bias, int soBias,
    u16* __restrict__ C, int ldc, int soC, int M, int K)
{
    int s = blockIdx.y;
    A1 += (size_t)s * soA1;
    if (DUAL) A2 += (size_t)s * soA2;
    B1 += (size_t)s * soB1;
    if (DUAL) B2 += (size_t)s * soB2;
    if (bias) bias += (size_t)s * soBias;
    C += (size_t)s * soC;

    int tid = threadIdx.x;
    int w = tid >> 6, l = tid & 63, l15 = l & 15, lg = l >> 4;
    int mbase = blockIdx.x * 64 + w * 16;
    int arow = mbase + l15; if (arow >= M) arow = M - 1;

    f32x4 acc[8];
#pragma unroll
    for (int nt = 0; nt < 8; nt++) {
        float bv = bias ? bias[16 * nt + l15] : 0.f;
        acc[nt] = (f32x4){bv, bv, bv, bv};
    }
    for (int k0 = 0; k0 < K; k0 += 32) {
        int k = k0 + 8 * lg;
        short8 a1 = *(const short8*)&A1[(size_t)arow * lda1 + k];
        short8 a2;
        if (DUAL) a2 = *(const short8*)&A2[(size_t)arow * lda2 + k];
#pragma unroll
        for (int nt = 0; nt < 8; nt++) {
            short8 b1 = *(const short8*)&B1[(size_t)(16 * nt + l15) * K + k];
            acc[nt] = __builtin_amdgcn_mfma_f32_16x16x32_bf16(a1, b1, acc[nt], 0, 0, 0);
            if (DUAL) {
                short8 b2 = *(const short8*)&B2[(size_t)(16 * nt + l15) * K + k];
                acc[nt] = __builtin_amdgcn_mfma_f32_16x16x32_bf16(a2, b2, acc[nt], 0, 0, 0);
            }
        }
    }
#pragma unroll
    for (int nt = 0; nt < 8; nt++)
#pragma unroll
    for (int r = 0; r < 4; r++) {
        int m = mbase + 4 * lg + r;
        if (m < M) {
            float v = acc[nt][r];
            if (ACT == 1) v = lrelu(v);
            C[(size_t)m * ldc + 16 * nt + l15] = f2bf(v);
        }
    }
}

// ---------------------------------------------------------------------------
// F0 packing: embedding gathers + ip  (cols 128..543; cols 0..127 by gemm)
// ---------------------------------------------------------------------------
__global__ void k_pack(const int* __restrict__ ic, const int* __restrict__ ico,
                       const int* __restrict__ isl, const float* __restrict__ ip,
                       const float* __restrict__ ecat, const float* __restrict__ ecou,
                       const float* __restrict__ esl, u16* __restrict__ F0) {
    int n = blockIdx.x, t = threadIdx.x;   // block 128
    u16* row = F0 + (size_t)n * 544;
    row[128 + t] = f2bf(ecat[(size_t)ic[n]  * 128 + t]);
    row[256 + t] = f2bf(ecou[(size_t)ico[n] * 128 + t]);
    row[384 + t] = f2bf(esl [(size_t)isl[n] * 128 + t]);
    if (t < 32) row[512 + t] = f2bf(ip[(size_t)n * 32 + t]);
}

// ---------------------------------------------------------------------------
// CSR build
// ---------------------------------------------------------------------------
__global__ void k_hist(const int* __restrict__ dst, int E, int* __restrict__ deg) {
    int e = blockIdx.x * 256 + threadIdx.x;
    if (e < E) atomicAdd(&deg[dst[e]], 1);
}
__global__ void k_scan(const int* __restrict__ deg, int* __restrict__ rowptr,
                       int* __restrict__ cursor, int n) {
    __shared__ int part[1024];
    int tid = threadIdx.x;
    const int CH = 10;
    int base = tid * CH;
    int s = 0;
#pragma unroll
    for (int i = 0; i < CH; i++) { int idx = base + i; if (idx < n) s += deg[idx]; }
    part[tid] = s; __syncthreads();
    for (int off = 1; off < 1024; off <<= 1) {
        int v = (tid >= off) ? part[tid - off] : 0;
        __syncthreads();
        part[tid] += v;
        __syncthreads();
    }
    int run = part[tid] - s;
    for (int i = 0; i < CH; i++) {
        int idx = base + i;
        if (idx < n) { rowptr[idx] = run; cursor[idx] = run; run += deg[idx]; }
    }
    if (tid == 1023) rowptr[n] = part[1023];
}
__global__ void k_fill(const int* __restrict__ src, const int* __restrict__ dst, int E,
                       int* __restrict__ cursor, int* __restrict__ colsrc) {
    int e = blockIdx.x * 256 + threadIdx.x;
    if (e < E) {
        int pos = atomicAdd(&cursor[dst[e]], 1);
        colsrc[pos] = src[e];
    }
}

// ---------------------------------------------------------------------------
// Mean aggregation: wave per node; degree loop software-pipelined x4 so four
// 1KB row-gathers are in flight (rows are L2/L3-resident; latency-bound).
// ---------------------------------------------------------------------------
__global__ __launch_bounds__(256) void k_agg(const u16* __restrict__ F, int C,
                                             const int* __restrict__ rowptr,
                                             const int* __restrict__ colsrc,
                                             u16* __restrict__ out, int N) {
    int w = threadIdx.x >> 6, l = threadIdx.x & 63;
    int n = blockIdx.x * 4 + w;
    if (n >= N) return;
    int chunks = C >> 3;
    int c0 = l, c1 = l + 64;
    bool has1 = c1 < chunks;
    float a0[8] = {0,0,0,0,0,0,0,0}, a1[8] = {0,0,0,0,0,0,0,0};
    int beg = rowptr[n], end = rowptr[n + 1];

    auto accum = [&](u32x4 v, float* a) {
#pragma unroll
        for (int j = 0; j < 4; j++) {
            u32 u = v[j];
            a[2*j]   += asf(u << 16);
            a[2*j+1] += asf(u & 0xffff0000u);
        }
    };

    int e = beg;
    for (; e + 4 <= end; e += 4) {
        int s0 = colsrc[e], s1 = colsrc[e+1], s2 = colsrc[e+2], s3 = colsrc[e+3];
        const u32x4* r0 = (const u32x4*)(F + (size_t)s0 * C);
        const u32x4* r1 = (const u32x4*)(F + (size_t)s1 * C);
        const u32x4* r2 = (const u32x4*)(F + (size_t)s2 * C);
        const u32x4* r3 = (const u32x4*)(F + (size_t)s3 * C);
        u32x4 v0 = r0[c0], v1 = r1[c0], v2 = r2[c0], v3 = r3[c0];
        if (has1) {
            u32x4 u0 = r0[c1], u1 = r1[c1], u2 = r2[c1], u3 = r3[c1];
            accum(v0, a0); accum(v1, a0); accum(v2, a0); accum(v3, a0);
            accum(u0, a1); accum(u1, a1); accum(u2, a1); accum(u3, a1);
        } else {
            accum(v0, a0); accum(v1, a0); accum(v2, a0); accum(v3, a0);
        }
    }
    for (; e < end; e++) {
        const u32x4* rp = (const u32x4*)(F + (size_t)colsrc[e] * C);
        accum(rp[c0], a0);
        if (has1) accum(rp[c1], a1);
    }

    int dg = end - beg; if (dg < 1) dg = 1;
    float inv = 1.f / (float)dg;
    u32x4 o0;
#pragma unroll
    for (int j = 0; j < 4; j++)
        o0[j] = (u32)f2bf(a0[2*j] * inv) | ((u32)f2bf(a0[2*j+1] * inv) << 16);
    ((u32x4*)(out + (size_t)n * C))[c0] = o0;
    if (has1) {
        u32x4 o1;
#pragma unroll
        for (int j = 0; j < 4; j++)
            o1[j] = (u32)f2bf(a1[2*j] * inv) | ((u32)f2bf(a1[2*j+1] * inv) << 16);
        ((u32x4*)(out + (size_t)n * C))[c1] = o1;
    }
}

// ---------------------------------------------------------------------------
// Attention fusion: wave per node. logits -> softmax(5) -> a, h = sum a*z.
// (attn_b is a constant shift -> softmax-invariant, skipped.)
// ---------------------------------------------------------------------------
__global__ __launch_bounds__(256) void k_attn(const u16* __restrict__ Z,
                                              const float* __restrict__ attnW,
                                              float* __restrict__ aOut,
                                              u16* __restrict__ hT, int N) {
    int w = threadIdx.x >> 6, l = threadIdx.x & 63;
    int n = blockIdx.x * 4 + w;
    if (n >= N) return;
    float wa0 = attnW[l], wa1 = attnW[l + 64];
    float z0[5], z1[5], lgt[5];
#pragma unroll
    for (int s = 0; s < 5; s++) {
        z0[s] = bf2f(Z[((size_t)(n * 5 + s)) * 128 + l]);
        z1[s] = bf2f(Z[((size_t)(n * 5 + s)) * 128 + l + 64]);
        float p = z0[s] * wa0 + z1[s] * wa1;
#pragma unroll
        for (int m = 1; m < 64; m <<= 1) p += __shfl_xor(p, m, 64);
        lgt[s] = p;
    }
    float mx = lgt[0];
#pragma unroll
    for (int s = 1; s < 5; s++) mx = fmaxf(mx, lgt[s]);
    float ex[5], sum = 0.f;
#pragma unroll
    for (int s = 0; s < 5; s++) { ex[s] = __expf(lgt[s] - mx); sum += ex[s]; }
    float a[5];
#pragma unroll
    for (int s = 0; s < 5; s++) a[s] = ex[s] / sum;
    float h0 = 0.f, h1 = 0.f;
#pragma unroll
    for (int s = 0; s < 5; s++) { h0 += a[s] * z0[s]; h1 += a[s] * z1[s]; }
    hT[(size_t)n * 128 + l] = f2bf(h0);
    hT[(size_t)n * 128 + l + 64] = f2bf(h1);
    if (l == 0) {
#pragma unroll
        for (int s = 0; s < 5; s++) aOut[(size_t)n * 5 + s] = a[s];
    }
}

// ---------------------------------------------------------------------------
// Edge MLP fused: score = lrelu([h_src|h_dst]@fcW + fcb)@fcoW + fcob
// wave per 16 edges; second matmul as in-register shfl reduce.
// ---------------------------------------------------------------------------
__global__ __launch_bounds__(256) void k_edge(const u16* __restrict__ hT,
                                              const int* __restrict__ esrc,
                                              const int* __restrict__ edst,
                                              const u16* __restrict__ fcWt,  // [128][256]
                                              const float* __restrict__ fcb,
                                              const float* __restrict__ fcoW, // [128][2]
                                              const float* __restrict__ fcob,
                                              float* __restrict__ score, int E2) {
    int tid = threadIdx.x;
    int w = tid >> 6, l = tid & 63, l15 = l & 15, lg = l >> 4;
    int eb = (blockIdx.x * 4 + w) * 16;
    int arow = eb + l15; if (arow >= E2) arow = E2 - 1;
    int sn = esrc[arow], dn = edst[arow];

    f32x4 acc[8];
#pragma unroll
    for (int nt = 0; nt < 8; nt++) {
        float bv = fcb[16 * nt + l15];
        acc[nt] = (f32x4){bv, bv, bv, bv};
    }
#pragma unroll
    for (int kk = 0; kk < 8; kk++) {
        int k = 32 * kk + 8 * lg;
        const u16* ap = (k < 128) ? &hT[(size_t)sn * 128 + k]
                                  : &hT[(size_t)dn * 128 + (k - 128)];
        short8 a = *(const short8*)ap;
#pragma unroll
        for (int nt = 0; nt < 8; nt++) {
            short8 b = *(const short8*)&fcWt[(size_t)(16 * nt + l15) * 256 + k];
            acc[nt] = __builtin_amdgcn_mfma_f32_16x16x32_bf16(a, b, acc[nt], 0, 0, 0);
        }
    }
    float p0[4] = {0,0,0,0}, p1[4] = {0,0,0,0};
#pragma unroll
    for (int nt = 0; nt < 8; nt++) {
        int c = 16 * nt + l15;
        float w0 = fcoW[c * 2], w1 = fcoW[c * 2 + 1];
#pragma unroll
        for (int r = 0; r < 4; r++) {
            float hd = lrelu(acc[nt][r]);
            p0[r] += hd * w0; p1[r] += hd * w1;
        }
    }
#pragma unroll
    for (int m = 1; m < 16; m <<= 1) {
#pragma unroll
        for (int r = 0; r < 4; r++) {
            p0[r] += __shfl_xor(p0[r], m, 64);
            p1[r] += __shfl_xor(p1[r], m, 64);
        }
    }
    if (l15 == 0) {
        float b0v = fcob[0], b1v = fcob[1];
#pragma unroll
        for (int r = 0; r < 4; r++) {
            int e = eb + 4 * lg + r;
            if (e < E2) {
                score[(size_t)e * 2 + 0] = p0[r] + b0v;
                score[(size_t)e * 2 + 1] = p1[r] + b1v;
            }
        }
    }
}

// ---------------------------------------------------------------------------
// attn_e output: [E2,2,5] both rows = a[e_src]
// ---------------------------------------------------------------------------
__global__ void k_attne(const float* __restrict__ a, const int* __restrict__ esrc,
                        float* __restrict__ out, int E2) {
    int m = blockIdx.x * 256 + threadIdx.x;
    if (m >= E2) return;
    int s = esrc[m];
#pragma unroll
    for (int i = 0; i < 5; i++) {
        float v = a[(size_t)s * 5 + i];
        out[(size_t)m * 10 + i] = v;
        out[(size_t)m * 10 + 5 + i] = v;
    }
}

// ---------------------------------------------------------------------------
extern "C" void kernel_launch(void* const* d_in, const int* in_sizes, int n_in,
                              void* d_out, int out_size, void* d_ws, size_t ws_size,
                              hipStream_t stream) {
    const int* inp_s   = (const int*)d_in[0];
    const int* inp_sm  = (const int*)d_in[1];
    const int* inp_c   = (const int*)d_in[2];
    const int* inp_co  = (const int*)d_in[3];
    const int* inp_sl  = (const int*)d_in[4];
    const float* inp_ip = (const float*)d_in[5];
    const int* blk_src = (const int*)d_in[6];
    const int* blk_dst = (const int*)d_in[7];
    const int* e_src   = (const int*)d_in[8];
    const int* e_dst   = (const int*)d_in[9];
    const float* emb_url = (const float*)d_in[10];
    const float* emb_cat = (const float*)d_in[11];
    const float* emb_cou = (const float*)d_in[12];
    const float* emb_sl  = (const float*)d_in[13];
    const float* Wih_f = (const float*)d_in[14];
    const float* Whh_f = (const float*)d_in[15];
    const float* b_f   = (const float*)d_in[16];
    const float* Wih_b = (const float*)d_in[17];
    const float* Whh_b = (const float*)d_in[18];
    const float* b_b   = (const float*)d_in[19];
    const float* fc_lstm_W = (const float*)d_in[20];
    const float* fc_lstm_b = (const float*)d_in[21];
    const float* attnlin_W = (const float*)d_in[22];
    const float* attn_W    = (const float*)d_in[23];
    /* d_in[24] attn_b: softmax shift-invariant, unused */
    const float* W0_self  = (const float*)d_in[25];
    const float* W0_neigh = (const float*)d_in[26];
    const float* b0       = (const float*)d_in[27];
    const float* Wip_self  = (const float*)d_in[28];
    const float* Wip_neigh = (const float*)d_in[29];
    const float* bip       = (const float*)d_in[30];
    const float* W1_self  = (const float*)d_in[31];
    const float* W1_neigh = (const float*)d_in[32];
    const float* b1       = (const float*)d_in[33];
    const float* fc_W  = (const float*)d_in[34];
    const float* fc_b  = (const float*)d_in[35];
    const float* fco_W = (const float*)d_in[36];
    const float* fco_b = (const float*)d_in[37];

    char* ws = (char*)d_ws;
    size_t off = 0;
    auto alloc = [&](size_t bytes) -> char* {
        char* p = ws + off;
        off += (bytes + 255) & ~(size_t)255;
        return p;
    };
    u16* xtab      = (u16*)alloc((size_t)2 * 128 * 512 * 2);
    u16* hcat      = (u16*)alloc((size_t)N_ * 256 * 2);
    u16* wt_fclstm = (u16*)alloc((size_t)128 * 256 * 2);
    u16* wt_w05s   = (u16*)alloc((size_t)5 * 128 * 128 * 2);  // 4 emb + padded ip
    u16* wt_w05n   = (u16*)alloc((size_t)5 * 128 * 128 * 2);
    u16* wt_w1s    = (u16*)alloc((size_t)5 * 128 * 128 * 2);
    u16* wt_w1n    = (u16*)alloc((size_t)5 * 128 * 128 * 2);
    u16* wt_attn   = (u16*)alloc((size_t)128 * 128 * 2);
    u16* wt_fc     = (u16*)alloc((size_t)128 * 256 * 2);
    float* bias5   = (float*)alloc((size_t)5 * 128 * 4);
    u16* F0        = (u16*)alloc((size_t)N_ * 544 * 2);
    u16* NEI       = (u16*)alloc((size_t)N_ * 640 * 2);
    u16* F1        = (u16*)alloc((size_t)N_ * 640 * 2);
    u16* H1        = (u16*)alloc((size_t)N_ * 640 * 2);
    u16* Zb        = (u16*)alloc((size_t)N_ * 5 * 128 * 2);
    u16* hT        = (u16*)alloc((size_t)N_ * 128 * 2);
    float* aA      = (float*)alloc((size_t)N_ * 5 * 4);
    int* deg       = (int*)alloc((size_t)N_ * 4);
    int* rowptr    = (int*)alloc((size_t)(N_ + 1) * 4);
    int* cursor    = (int*)alloc((size_t)N_ * 4);
    int* colsrc    = (int*)alloc((size_t)E_ * 4);
    (void)ws_size; (void)in_sizes; (void)n_in; (void)out_size;

    float* out_score = (float*)d_out;
    float* out_attne = out_score + (size_t)2 * E2_;

    // --- CSR build ---
    hipMemsetAsync(deg, 0, (size_t)N_ * 4, stream);
    k_hist<<<dim3((E_ + 255) / 256), dim3(256), 0, stream>>>(blk_dst, E_, deg);
    k_scan<<<dim3(1), dim3(1024), 0, stream>>>(deg, rowptr, cursor, N_);
    k_fill<<<dim3((E_ + 255) / 256), dim3(256), 0, stream>>>(blk_src, blk_dst, E_, cursor, colsrc);

    // --- LSTM prep + run ---
    k_xtab<<<dim3(128, 2), dim3(512), 0, stream>>>(emb_url, Wih_f, b_f, Wih_b, b_b, xtab);
    {
        WtArgs a;
        a.seg[0] = {fc_lstm_W, wt_fclstm,            256, 256, 128, 1 * 128 * 256};
        a.seg[1] = {W0_self,   wt_w05s,              128, 128, 128, 4 * 128 * 128};
        a.seg[2] = {W0_neigh,  wt_w05n,              128, 128, 128, 4 * 128 * 128};
        a.seg[3] = {Wip_self,  wt_w05s + 4 * 16384,  128,  32, 128, 1 * 128 * 128};
        a.seg[4] = {Wip_neigh, wt_w05n + 4 * 16384,  128,  32, 128, 1 * 128 * 128};
        a.seg[5] = {W1_self,   wt_w1s,               128, 128, 128, 5 * 128 * 128};
        a.seg[6] = {W1_neigh,  wt_w1n,               128, 128, 128, 5 * 128 * 128};
        a.seg[7] = {attnlin_W, wt_attn,              128, 128, 128, 1 * 128 * 128};
        a.seg[8] = {fc_W,      wt_fc,                256, 256, 128, 1 * 128 * 256};
        k_wt_all<<<dim3((5 * 128 * 128 + 255) / 256, 9), dim3(256), 0, stream>>>(a);
    }
    // combined bias [5][128] = b0 (4x128) | bip (128)
    hipMemcpyAsync(bias5, b0, 512 * sizeof(float), hipMemcpyDeviceToDevice, stream);
    hipMemcpyAsync(bias5 + 512, bip, 128 * sizeof(float), hipMemcpyDeviceToDevice, stream);

    k_lstm<<<dim3(N_ / 16, 2), dim3(512), 0, stream>>>(xtab, inp_s, inp_sm, Whh_f, Whh_b, hcat);

    // vec_url = lrelu(hcat @ fc_lstm_W + b) -> F0 cols [0,128)
    k_gemm<1, 0><<<dim3((N_ + 63) / 64, 1), dim3(256), 0, stream>>>(
        hcat, 256, 0, nullptr, 0, 0, wt_fclstm, 0, nullptr, 0,
        fc_lstm_b, 0, F0, 544, 0, N_, 256);
    k_pack<<<dim3(N_), dim3(128), 0, stream>>>(inp_c, inp_co, inp_sl, inp_ip,
                                               emb_cat, emb_cou, emb_sl, F0);

    // --- SAGE layer 0: all 5 streams (ip K-padded to 128) in one dispatch ---
    k_agg<<<dim3(N_ / 4), dim3(256), 0, stream>>>(F0, 544, rowptr, colsrc, NEI, N_);
    k_gemm<1, 1><<<dim3((N_ + 63) / 64, 5), dim3(256), 0, stream>>>(
        F0, 544, 128, NEI, 544, 128, wt_w05s, 128 * 128, wt_w05n, 128 * 128,
        bias5, 128, F1, 640, 128, N_, 128);

    // --- SAGE layer 1 ---
    k_agg<<<dim3(N_ / 4), dim3(256), 0, stream>>>(F1, 640, rowptr, colsrc, NEI, N_);
    k_gemm<1, 1><<<dim3((N_ + 63) / 64, 5), dim3(256), 0, stream>>>(
        F1, 640, 128, NEI, 640, 128, wt_w1s, 128 * 128, wt_w1n, 128 * 128,
        b1, 128, H1, 640, 128, N_, 128);

    // --- attention ---
    // z: [N*5,128] = H1 @ attnlin_W  (H1 rows are exactly (n,s) pairs)
    k_gemm<0, 0><<<dim3((N_ * 5 + 63) / 64, 1), dim3(256), 0, stream>>>(
        H1, 128, 0, nullptr, 0, 0, wt_attn, 0, nullptr, 0,
        nullptr, 0, Zb, 128, 0, N_ * 5, 128);
    k_attn<<<dim3(N_ / 4), dim3(256), 0, stream>>>(Zb, attn_W, aA, hT, N_);

    // --- edge scoring ---
    k_edge<<<dim3(E2_ / 64), dim3(256), 0, stream>>>(hT, e_src, e_dst, wt_fc, fc_b,
                                                     fco_W, fco_b, out_score, E2_);
    k_attne<<<dim3(E2_ / 256), dim3(256), 0, stream>>>(aA, e_src, out_attne, E2_);
}

// Round 6
// 587.354 us; speedup vs baseline: 1.2024x; 1.0171x over previous
//
#include <hip/hip_runtime.h>
#include <hip/hip_bf16.h>
#include <stdint.h>

typedef unsigned short u16;
typedef unsigned int   u32;
typedef __attribute__((ext_vector_type(8))) short short8;   // 8 bf16 = MFMA A/B frag
typedef __attribute__((ext_vector_type(4))) float f32x4;    // MFMA C/D frag
typedef __attribute__((ext_vector_type(2))) u32   u32x2;
typedef __attribute__((ext_vector_type(4))) u32   u32x4;

#define DEV static __device__ __forceinline__

constexpr int N_  = 10000;
constexpr int T_  = 32;
constexpr int E_  = 320000;
constexpr int E2_ = 160000;

DEV u16 f2bf(float f) {
    union { float f; u32 u; } v; v.f = f;
    u32 u = v.u;
    return (u16)((u + 0x7fffu + ((u >> 16) & 1u)) >> 16);   // RNE
}
DEV float bf2f(u16 h) {
    union { u32 u; float f; } v; v.u = ((u32)h) << 16; return v.f;
}
DEV float asf(u32 u) {
    union { u32 u; float f; } v; v.u = u; return v.f;
}
DEV u32 cvt_pk_bf16(float lo, float hi) {
    u32 r;
    asm("v_cvt_pk_bf16_f32 %0, %1, %2" : "=v"(r) : "v"(lo), "v"(hi));
    return r;
}
DEV float lrelu(float x) { return x > 0.f ? x : 0.01f * x; }

DEV float fexp2(float x) {
#if __has_builtin(__builtin_amdgcn_exp2f)
    return __builtin_amdgcn_exp2f(x);
#else
    return exp2f(x);
#endif
}
DEV float frcp(float x) {
#if __has_builtin(__builtin_amdgcn_rcpf)
    return __builtin_amdgcn_rcpf(x);
#else
    return 1.0f / x;
#endif
}
DEV float fsig(float x)  { return frcp(1.f + fexp2(-1.4426950408889634f * x)); }
DEV float ftanh_(float x){ return 1.f - 2.f * frcp(1.f + fexp2(2.8853900817779268f * x)); }

// ---------------------------------------------------------------------------
// xtab[dir][sym][512] = emb_url[sym] @ Wih.T + b   (bf16)
// ---------------------------------------------------------------------------
__global__ void k_xtab(const float* __restrict__ emb,
                       const float* __restrict__ WihF, const float* __restrict__ bF,
                       const float* __restrict__ WihB, const float* __restrict__ bB,
                       u16* __restrict__ xtab) {
    int sym = blockIdx.x, dir = blockIdx.y, o = threadIdx.x;   // block 512
    const float* W = dir ? WihB : WihF;
    const float* b = dir ? bB : bF;
    __shared__ float er[128];
    if (o < 128) er[o] = emb[sym * 128 + o];
    __syncthreads();
    float s = b[o];
    for (int k = 0; k < 128; k++) s += er[k] * W[o * 128 + k];
    xtab[((size_t)(dir * 128 + sym)) * 512 + o] = f2bf(s);
}

// ---------------------------------------------------------------------------
// Merged weight transpose+convert (with K zero-padding for the ip stream):
// W fp32 [S][Ks][Nw] -> out bf16 [S][Nw][Kd], k>=Ks zero-filled.
// ---------------------------------------------------------------------------
struct WtSeg { const float* W; u16* out; int Kd, Ks, Nw, tot; };
struct WtArgs { WtSeg seg[9]; };
__global__ void k_wt_all(WtArgs a) {
    WtSeg sg = a.seg[blockIdx.y];
    int i = blockIdx.x * 256 + threadIdx.x;
    if (i >= sg.tot) return;
    int k = i % sg.Kd, n = (i / sg.Kd) % sg.Nw, s = i / (sg.Kd * sg.Nw);
    float v = (k < sg.Ks) ? sg.W[((size_t)s * sg.Ks + k) * sg.Nw + n] : 0.f;
    sg.out[i] = f2bf(v);
}

// ---------------------------------------------------------------------------
// Bi-LSTM: block = 512 threads (8 waves) x 16 sequences, one direction.
// Wave w owns hidden units [16w,16w+16) for all 4 gates (64 VGPR of Whh).
// h in LDS fragment-major, double-buffered. This round: RAW barrier
// (s_waitcnt lgkmcnt(0) + s_barrier) instead of __syncthreads -> the xtab
// global prefetch is NOT drained at each step (vmcnt spans the barrier);
// xt prefetch loads into the SAME regs right after acc-init consumes them.
// ---------------------------------------------------------------------------
__global__ __launch_bounds__(512, 2) void k_lstm(
    const u16* __restrict__ xtab,      // [2][128][512] bf16 (bias folded)
    const int* __restrict__ syms,      // [N][32]
    const int* __restrict__ smask,     // [N][32]
    const float* __restrict__ WhhF,    // [512][128]
    const float* __restrict__ WhhB,
    u16* __restrict__ hcat)            // [N][256] bf16 (fwd | bwd)
{
    __shared__ u16 h_buf0[2048];       // [16 slabs][16 seq][8 elems]
    __shared__ u16 h_buf1[2048];
    __shared__ int sym_l[512];         // [t][seq]
    __shared__ int msk_l[512];         // [t][seq]

    int tid = threadIdx.x;
    int w = tid >> 6, l = tid & 63, l15 = l & 15, lg = l >> 4;
    int dir = blockIdx.y;
    int n0 = blockIdx.x * 16;
    const float* Whh = dir ? WhhB : WhhF;

    for (int i = tid; i < 512; i += 512) {
        int seq = i >> 5, t = i & 31;
        sym_l[t * 16 + seq] = syms[(size_t)n0 * 32 + i];
        msk_l[t * 16 + seq] = smask[(size_t)n0 * 32 + i];
    }
    for (int i = tid; i < 2048; i += 512) h_buf0[i] = 0;

    // A fragments: wave w covers gate gg, units 128*gg + 16*w + row
    short8 aw[4][4];
#pragma unroll
    for (int gg = 0; gg < 4; gg++)
#pragma unroll
    for (int kk = 0; kk < 4; kk++) {
        const float* p = Whh + (size_t)(128 * gg + 16 * w + l15) * 128 + 32 * kk + 8 * lg;
        const float4* pp = (const float4*)p;
        float4 x0 = pp[0], x1 = pp[1];
        short8 v;
        v[0] = (short)f2bf(x0.x); v[1] = (short)f2bf(x0.y);
        v[2] = (short)f2bf(x0.z); v[3] = (short)f2bf(x0.w);
        v[4] = (short)f2bf(x1.x); v[5] = (short)f2bf(x1.y);
        v[6] = (short)f2bf(x1.z); v[7] = (short)f2bf(x1.w);
        aw[gg][kk] = v;
    }

    float hreg[4] = {0, 0, 0, 0};
    float creg[4] = {0, 0, 0, 0};
    int jb = 16 * w + 4 * lg;          // hidden-unit base for this lane
    int wsk = 2 * w + (lg >> 1);       // write slab index (= jb>>3)
    int wof = (wsk * 16 + l15) * 8 + 4 * (lg & 1);
    const u16* xbase = xtab + (size_t)dir * 128 * 512 + jb;
    __syncthreads();

    u32x2 xt[4];
    {   // prologue: prefetch xtab gate inputs for step 0
        int t0 = dir ? 31 : 0;
        int sym0 = sym_l[t0 * 16 + l15];
        const u16* xr = xbase + (size_t)sym0 * 512;
#pragma unroll
        for (int gg = 0; gg < 4; gg++) xt[gg] = *(const u32x2*)(xr + gg * 128);
    }

    auto step = [&](int st, const u16* rb, u16* wb) {
        int t = dir ? (31 - st) : st;

        // B fragments: contiguous 1KB slab per wave, conflict-free
        short8 bh[4];
#pragma unroll
        for (int kk = 0; kk < 4; kk++)
            bh[kk] = *(const short8*)&rb[((kk * 4 + lg) * 16 + l15) * 8];

        f32x4 acc[4];
#pragma unroll
        for (int gg = 0; gg < 4; gg++) {
            // init C with the xtab gate inputs (x@Wih.T + b)
            f32x4 a = { asf(xt[gg][0] << 16), asf(xt[gg][0] & 0xffff0000u),
                        asf(xt[gg][1] << 16), asf(xt[gg][1] & 0xffff0000u) };
#pragma unroll
            for (int kk = 0; kk < 4; kk++)
                a = __builtin_amdgcn_mfma_f32_16x16x32_bf16(aw[gg][kk], bh[kk], a, 0, 0, 0);
            acc[gg] = a;
        }

        // prefetch next step's xtab inputs into the SAME regs (last use was
        // acc-init above); completion awaited only at next step's acc-init,
        // and the raw barrier below does NOT drain vmcnt.
        {
            int stn = (st < 31) ? (st + 1) : 31;
            int tn = dir ? (31 - stn) : stn;
            int symn = sym_l[tn * 16 + l15];
            const u16* xr = xbase + (size_t)symn * 512;
#pragma unroll
            for (int gg = 0; gg < 4; gg++) xt[gg] = *(const u32x2*)(xr + gg * 128);
        }

        int mt_i = msk_l[t * 16 + l15];
        bool mb = mt_i != 0;
#pragma unroll
        for (int r = 0; r < 4; r++) {
            float i_ = fsig(acc[0][r]), f_ = fsig(acc[1][r]);
            float g_ = ftanh_(acc[2][r]), o_ = fsig(acc[3][r]);
            float cn = f_ * creg[r] + i_ * g_;
            float hn = o_ * ftanh_(cn);
            hreg[r] = mb ? hn : hreg[r];
            creg[r] = mb ? cn : creg[r];
        }
        u32x2 pk;
        pk[0] = cvt_pk_bf16(hreg[0], hreg[1]);
        pk[1] = cvt_pk_bf16(hreg[2], hreg[3]);
        *(u32x2*)&wb[wof] = pk;
        // raw barrier: wait only LDS ops (my ds_write retired), NOT vmcnt
        asm volatile("s_waitcnt lgkmcnt(0)" ::: "memory");
        __builtin_amdgcn_s_barrier();
    };

    for (int st2 = 0; st2 < 16; st2++) {
        step(2 * st2,     h_buf0, h_buf1);
        step(2 * st2 + 1, h_buf1, h_buf0);
    }

    // final hidden -> hcat[n][dir*128 + j]
    {
        u32x2 pk;
        pk[0] = cvt_pk_bf16(hreg[0], hreg[1]);
        pk[1] = cvt_pk_bf16(hreg[2], hreg[3]);
        *(u32x2*)&hcat[(size_t)(n0 + l15) * 256 + dir * 128 + jb] = pk;
    }
}

// ---------------------------------------------------------------------------
// Generic MFMA GEMM: C[M,128] = act(A1@B1 [+ A2@B2] + bias), bf16 in/out.
// B pre-transposed bf16 [128][K]. Block = 4 waves x 16 rows.
// blockIdx.y = stream index s; so* are per-stream element offsets.
// ---------------------------------------------------------------------------
template<int ACT, int DUAL>
__global__ __launch_bounds__(256) void k_gemm(
    const u16* __restrict__ A1, int lda1, int soA1,
    const u16* __restrict__ A2, int lda2, int soA2,
    const u16* __restrict__ B1, int soB1,
    const u16* __restrict__ B2, int soB2,
    const float* __restrict__ bias, int soBias,
    u16* __restrict__ C, int ldc, int soC, int M, int K)
{
    int s = blockIdx.y;
    A1 += (size_t)s * soA1;
    if (DUAL) A2 += (size_t)s * soA2;
    B1 += (size_t)s * soB1;
    if (DUAL) B2 += (size_t)s * soB2;
    if (bias) bias += (size_t)s * soBias;
    C += (size_t)s * soC;

    int tid = threadIdx.x;
    int w = tid >> 6, l = tid & 63, l15 = l & 15, lg = l >> 4;
    int mbase = blockIdx.x * 64 + w * 16;
    int arow = mbase + l15; if (arow >= M) arow = M - 1;

    f32x4 acc[8];
#pragma unroll
    for (int nt = 0; nt < 8; nt++) {
        float bv = bias ? bias[16 * nt + l15] : 0.f;
        acc[nt] = (f32x4){bv, bv, bv, bv};
    }
    for (int k0 = 0; k0 < K; k0 += 32) {
        int k = k0 + 8 * lg;
        short8 a1 = *(const short8*)&A1[(size_t)arow * lda1 + k];
        short8 a2;
        if (DUAL) a2 = *(const short8*)&A2[(size_t)arow * lda2 + k];
#pragma unroll
        for (int nt = 0; nt < 8; nt++) {
            short8 b1 = *(const short8*)&B1[(size_t)(16 * nt + l15) * K + k];
            acc[nt] = __builtin_amdgcn_mfma_f32_16x16x32_bf16(a1, b1, acc[nt], 0, 0, 0);
            if (DUAL) {
                short8 b2 = *(const short8*)&B2[(size_t)(16 * nt + l15) * K + k];
                acc[nt] = __builtin_amdgcn_mfma_f32_16x16x32_bf16(a2, b2, acc[nt], 0, 0, 0);
            }
        }
    }
#pragma unroll
    for (int nt = 0; nt < 8; nt++)
#pragma unroll
    for (int r = 0; r < 4; r++) {
        int m = mbase + 4 * lg + r;
        if (m < M) {
            float v = acc[nt][r];
            if (ACT == 1) v = lrelu(v);
            C[(size_t)m * ldc + 16 * nt + l15] = f2bf(v);
        }
    }
}

// ---------------------------------------------------------------------------
// F0 packing: embedding gathers + ip  (cols 128..543; cols 0..127 by gemm)
// ---------------------------------------------------------------------------
__global__ void k_pack(const int* __restrict__ ic, const int* __restrict__ ico,
                       const int* __restrict__ isl, const float* __restrict__ ip,
                       const float* __restrict__ ecat, const float* __restrict__ ecou,
                       const float* __restrict__ esl, u16* __restrict__ F0) {
    int n = blockIdx.x, t = threadIdx.x;   // block 128
    u16* row = F0 + (size_t)n * 544;
    row[128 + t] = f2bf(ecat[(size_t)ic[n]  * 128 + t]);
    row[256 + t] = f2bf(ecou[(size_t)ico[n] * 128 + t]);
    row[384 + t] = f2bf(esl [(size_t)isl[n] * 128 + t]);
    if (t < 32) row[512 + t] = f2bf(ip[(size_t)n * 32 + t]);
}

// ---------------------------------------------------------------------------
// CSR build
// ---------------------------------------------------------------------------
__global__ void k_hist(const int* __restrict__ dst, int E, int* __restrict__ deg) {
    int e = blockIdx.x * 256 + threadIdx.x;
    if (e < E) atomicAdd(&deg[dst[e]], 1);
}
__global__ void k_scan(const int* __restrict__ deg, int* __restrict__ rowptr,
                       int* __restrict__ cursor, int n) {
    __shared__ int part[1024];
    int tid = threadIdx.x;
    const int CH = 10;
    int base = tid * CH;
    int s = 0;
#pragma unroll
    for (int i = 0; i < CH; i++) { int idx = base + i; if (idx < n) s += deg[idx]; }
    part[tid] = s; __syncthreads();
    for (int off = 1; off < 1024; off <<= 1) {
        int v = (tid >= off) ? part[tid - off] : 0;
        __syncthreads();
        part[tid] += v;
        __syncthreads();
    }
    int run = part[tid] - s;
    for (int i = 0; i < CH; i++) {
        int idx = base + i;
        if (idx < n) { rowptr[idx] = run; cursor[idx] = run; run += deg[idx]; }
    }
    if (tid == 1023) rowptr[n] = part[1023];
}
__global__ void k_fill(const int* __restrict__ src, const int* __restrict__ dst, int E,
                       int* __restrict__ cursor, int* __restrict__ colsrc) {
    int e = blockIdx.x * 256 + threadIdx.x;
    if (e < E) {
        int pos = atomicAdd(&cursor[dst[e]], 1);
        colsrc[pos] = src[e];
    }
}

// ---------------------------------------------------------------------------
// Mean aggregation: wave per node; 8-deep load pipelining (16 u32x4 gathers
// in flight per wave) against L2/L3 latency.
// ---------------------------------------------------------------------------
__global__ __launch_bounds__(256) void k_agg(const u16* __restrict__ F, int C,
                                             const int* __restrict__ rowptr,
                                             const int* __restrict__ colsrc,
                                             u16* __restrict__ out, int N) {
    int w = threadIdx.x >> 6, l = threadIdx.x & 63;
    int n = blockIdx.x * 4 + w;
    if (n >= N) return;
    int chunks = C >> 3;
    int c0 = l, c1 = l + 64;
    bool has1 = c1 < chunks;
    float a0[8] = {0,0,0,0,0,0,0,0}, a1[8] = {0,0,0,0,0,0,0,0};
    int beg = rowptr[n], end = rowptr[n + 1];

    auto accum = [&](u32x4 v, float* a) {
#pragma unroll
        for (int j = 0; j < 4; j++) {
            u32 u = v[j];
            a[2*j]   += asf(u << 16);
            a[2*j+1] += asf(u & 0xffff0000u);
        }
    };

    int e = beg;
    for (; e + 8 <= end; e += 8) {
        const u32x4* rp[8];
#pragma unroll
        for (int j = 0; j < 8; j++)
            rp[j] = (const u32x4*)(F + (size_t)colsrc[e + j] * C);
        u32x4 v[8];
#pragma unroll
        for (int j = 0; j < 8; j++) v[j] = rp[j][c0];
        if (has1) {
            u32x4 u[8];
#pragma unroll
            for (int j = 0; j < 8; j++) u[j] = rp[j][c1];
#pragma unroll
            for (int j = 0; j < 8; j++) accum(v[j], a0);
#pragma unroll
            for (int j = 0; j < 8; j++) accum(u[j], a1);
        } else {
#pragma unroll
            for (int j = 0; j < 8; j++) accum(v[j], a0);
        }
    }
    for (; e + 4 <= end; e += 4) {
        const u32x4* rp[4];
#pragma unroll
        for (int j = 0; j < 4; j++)
            rp[j] = (const u32x4*)(F + (size_t)colsrc[e + j] * C);
        u32x4 v[4];
#pragma unroll
        for (int j = 0; j < 4; j++) v[j] = rp[j][c0];
        if (has1) {
            u32x4 u[4];
#pragma unroll
            for (int j = 0; j < 4; j++) u[j] = rp[j][c1];
#pragma unroll
            for (int j = 0; j < 4; j++) accum(v[j], a0);
#pragma unroll
            for (int j = 0; j < 4; j++) accum(u[j], a1);
        } else {
#pragma unroll
            for (int j = 0; j < 4; j++) accum(v[j], a0);
        }
    }
    for (; e < end; e++) {
        const u32x4* rp = (const u32x4*)(F + (size_t)colsrc[e] * C);
        accum(rp[c0], a0);
        if (has1) accum(rp[c1], a1);
    }

    int dg = end - beg; if (dg < 1) dg = 1;
    float inv = 1.f / (float)dg;
    u32x4 o0;
#pragma unroll
    for (int j = 0; j < 4; j++)
        o0[j] = (u32)f2bf(a0[2*j] * inv) | ((u32)f2bf(a0[2*j+1] * inv) << 16);
    ((u32x4*)(out + (size_t)n * C))[c0] = o0;
    if (has1) {
        u32x4 o1;
#pragma unroll
        for (int j = 0; j < 4; j++)
            o1[j] = (u32)f2bf(a1[2*j] * inv) | ((u32)f2bf(a1[2*j+1] * inv) << 16);
        ((u32x4*)(out + (size_t)n * C))[c1] = o1;
    }
}

// ---------------------------------------------------------------------------
// Attention fusion: wave per node. logits -> softmax(5) -> a, h = sum a*z.
// (attn_b is a constant shift -> softmax-invariant, skipped.)
// ---------------------------------------------------------------------------
__global__ __launch_bounds__(256) void k_attn(const u16* __restrict__ Z,
                                              const float* __restrict__ attnW,
                                              float* __restrict__ aOut,
                                              u16* __restrict__ hT, int N) {
    int w = threadIdx.x >> 6, l = threadIdx.x & 63;
    int n = blockIdx.x * 4 + w;
    if (n >= N) return;
    float wa0 = attnW[l], wa1 = attnW[l + 64];
    float z0[5], z1[5], lgt[5];
#pragma unroll
    for (int s = 0; s < 5; s++) {
        z0[s] = bf2f(Z[((size_t)(n * 5 + s)) * 128 + l]);
        z1[s] = bf2f(Z[((size_t)(n * 5 + s)) * 128 + l + 64]);
        float p = z0[s] * wa0 + z1[s] * wa1;
#pragma unroll
        for (int m = 1; m < 64; m <<= 1) p += __shfl_xor(p, m, 64);
        lgt[s] = p;
    }
    float mx = lgt[0];
#pragma unroll
    for (int s = 1; s < 5; s++) mx = fmaxf(mx, lgt[s]);
    float ex[5], sum = 0.f;
#pragma unroll
    for (int s = 0; s < 5; s++) { ex[s] = __expf(lgt[s] - mx); sum += ex[s]; }
    float a[5];
#pragma unroll
    for (int s = 0; s < 5; s++) a[s] = ex[s] / sum;
    float h0 = 0.f, h1 = 0.f;
#pragma unroll
    for (int s = 0; s < 5; s++) { h0 += a[s] * z0[s]; h1 += a[s] * z1[s]; }
    hT[(size_t)n * 128 + l] = f2bf(h0);
    hT[(size_t)n * 128 + l + 64] = f2bf(h1);
    if (l == 0) {
#pragma unroll
        for (int s = 0; s < 5; s++) aOut[(size_t)n * 5 + s] = a[s];
    }
}

// ---------------------------------------------------------------------------
// Edge MLP fused: score = lrelu([h_src|h_dst]@fcW + fcb)@fcoW + fcob
// wave per 16 edges; second matmul as in-register shfl reduce.
// attn_e output fused in (both rows = a[e_src]).
// ---------------------------------------------------------------------------
__global__ __launch_bounds__(256) void k_edge(const u16* __restrict__ hT,
                                              const int* __restrict__ esrc,
                                              const int* __restrict__ edst,
                                              const u16* __restrict__ fcWt,  // [128][256]
                                              const float* __restrict__ fcb,
                                              const float* __restrict__ fcoW, // [128][2]
                                              const float* __restrict__ fcob,
                                              const float* __restrict__ aA,   // [N][5]
                                              float* __restrict__ score,      // [E2][2]
                                              float* __restrict__ attne,      // [E2][2][5]
                                              int E2) {
    int tid = threadIdx.x;
    int w = tid >> 6, l = tid & 63, l15 = l & 15, lg = l >> 4;
    int eb = (blockIdx.x * 4 + w) * 16;
    int arow = eb + l15; if (arow >= E2) arow = E2 - 1;
    int sn = esrc[arow], dn = edst[arow];

    f32x4 acc[8];
#pragma unroll
    for (int nt = 0; nt < 8; nt++) {
        float bv = fcb[16 * nt + l15];
        acc[nt] = (f32x4){bv, bv, bv, bv};
    }
#pragma unroll
    for (int kk = 0; kk < 8; kk++) {
        int k = 32 * kk + 8 * lg;
        const u16* ap = (k < 128) ? &hT[(size_t)sn * 128 + k]
                                  : &hT[(size_t)dn * 128 + (k - 128)];
        short8 a = *(const short8*)ap;
#pragma unroll
        for (int nt = 0; nt < 8; nt++) {
            short8 b = *(const short8*)&fcWt[(size_t)(16 * nt + l15) * 256 + k];
            acc[nt] = __builtin_amdgcn_mfma_f32_16x16x32_bf16(a, b, acc[nt], 0, 0, 0);
        }
    }
    float p0[4] = {0,0,0,0}, p1[4] = {0,0,0,0};
#pragma unroll
    for (int nt = 0; nt < 8; nt++) {
        int c = 16 * nt + l15;
        float w0 = fcoW[c * 2], w1 = fcoW[c * 2 + 1];
#pragma unroll
        for (int r = 0; r < 4; r++) {
            float hd = lrelu(acc[nt][r]);
            p0[r] += hd * w0; p1[r] += hd * w1;
        }
    }
#pragma unroll
    for (int m = 1; m < 16; m <<= 1) {
#pragma unroll
        for (int r = 0; r < 4; r++) {
            p0[r] += __shfl_xor(p0[r], m, 64);
            p1[r] += __shfl_xor(p1[r], m, 64);
        }
    }
    if (l15 == 0) {
        float b0v = fcob[0], b1v = fcob[1];
#pragma unroll
        for (int r = 0; r < 4; r++) {
            int e = eb + 4 * lg + r;
            if (e < E2) {
                score[(size_t)e * 2 + 0] = p0[r] + b0v;
                score[(size_t)e * 2 + 1] = p1[r] + b1v;
            }
        }
    }
    // fused attn_e: wave covers 16 edges x 10 floats, coalesced writes
#pragma unroll
    for (int pass = 0; pass < 3; pass++) {
        int idx = pass * 64 + l;
        if (idx < 160) {
            int e = eb + idx / 10;
            int j = idx % 10;
            int s = esrc[e];
            attne[(size_t)e * 10 + j] = aA[(size_t)s * 5 + (j >= 5 ? j - 5 : j)];
        }
    }
}

// ---------------------------------------------------------------------------
extern "C" void kernel_launch(void* const* d_in, const int* in_sizes, int n_in,
                              void* d_out, int out_size, void* d_ws, size_t ws_size,
                              hipStream_t stream) {
    const int* inp_s   = (const int*)d_in[0];
    const int* inp_sm  = (const int*)d_in[1];
    const int* inp_c   = (const int*)d_in[2];
    const int* inp_co  = (const int*)d_in[3];
    const int* inp_sl  = (const int*)d_in[4];
    const float* inp_ip = (const float*)d_in[5];
    const int* blk_src = (const int*)d_in[6];
    const int* blk_dst = (const int*)d_in[7];
    const int* e_src   = (const int*)d_in[8];
    const int* e_dst   = (const int*)d_in[9];
    const float* emb_url = (const float*)d_in[10];
    const float* emb_cat = (const float*)d_in[11];
    const float* emb_cou = (const float*)d_in[12];
    const float* emb_sl  = (const float*)d_in[13];
    const float* Wih_f = (const float*)d_in[14];
    const float* Whh_f = (const float*)d_in[15];
    const float* b_f   = (const float*)d_in[16];
    const float* Wih_b = (const float*)d_in[17];
    const float* Whh_b = (const float*)d_in[18];
    const float* b_b   = (const float*)d_in[19];
    const float* fc_lstm_W = (const float*)d_in[20];
    const float* fc_lstm_b = (const float*)d_in[21];
    const float* attnlin_W = (const float*)d_in[22];
    const float* attn_W    = (const float*)d_in[23];
    /* d_in[24] attn_b: softmax shift-invariant, unused */
    const float* W0_self  = (const float*)d_in[25];
    const float* W0_neigh = (const float*)d_in[26];
    const float* b0       = (const float*)d_in[27];
    const float* Wip_self  = (const float*)d_in[28];
    const float* Wip_neigh = (const float*)d_in[29];
    const float* bip       = (const float*)d_in[30];
    const float* W1_self  = (const float*)d_in[31];
    const float* W1_neigh = (const float*)d_in[32];
    const float* b1       = (const float*)d_in[33];
    const float* fc_W  = (const float*)d_in[34];
    const float* fc_b  = (const float*)d_in[35];
    const float* fco_W = (const float*)d_in[36];
    const float* fco_b = (const float*)d_in[37];

    char* ws = (char*)d_ws;
    size_t off = 0;
    auto alloc = [&](size_t bytes) -> char* {
        char* p = ws + off;
        off += (bytes + 255) & ~(size_t)255;
        return p;
    };
    u16* xtab      = (u16*)alloc((size_t)2 * 128 * 512 * 2);
    u16* hcat      = (u16*)alloc((size_t)N_ * 256 * 2);
    u16* wt_fclstm = (u16*)alloc((size_t)128 * 256 * 2);
    u16* wt_w05s   = (u16*)alloc((size_t)5 * 128 * 128 * 2);  // 4 emb + padded ip
    u16* wt_w05n   = (u16*)alloc((size_t)5 * 128 * 128 * 2);
    u16* wt_w1s    = (u16*)alloc((size_t)5 * 128 * 128 * 2);
    u16* wt_w1n    = (u16*)alloc((size_t)5 * 128 * 128 * 2);
    u16* wt_attn   = (u16*)alloc((size_t)128 * 128 * 2);
    u16* wt_fc     = (u16*)alloc((size_t)128 * 256 * 2);
    float* bias5   = (float*)alloc((size_t)5 * 128 * 4);
    u16* F0        = (u16*)alloc((size_t)N_ * 544 * 2);
    u16* NEI       = (u16*)alloc((size_t)N_ * 640 * 2);
    u16* F1        = (u16*)alloc((size_t)N_ * 640 * 2);
    u16* H1        = (u16*)alloc((size_t)N_ * 640 * 2);
    u16* Zb        = (u16*)alloc((size_t)N_ * 5 * 128 * 2);
    u16* hT        = (u16*)alloc((size_t)N_ * 128 * 2);
    float* aA      = (float*)alloc((size_t)N_ * 5 * 4);
    int* deg       = (int*)alloc((size_t)N_ * 4);
    int* rowptr    = (int*)alloc((size_t)(N_ + 1) * 4);
    int* cursor    = (int*)alloc((size_t)N_ * 4);
    int* colsrc    = (int*)alloc((size_t)E_ * 4);
    (void)ws_size; (void)in_sizes; (void)n_in; (void)out_size;

    float* out_score = (float*)d_out;
    float* out_attne = out_score + (size_t)2 * E2_;

    // --- CSR build ---
    hipMemsetAsync(deg, 0, (size_t)N_ * 4, stream);
    k_hist<<<dim3((E_ + 255) / 256), dim3(256), 0, stream>>>(blk_dst, E_, deg);
    k_scan<<<dim3(1), dim3(1024), 0, stream>>>(deg, rowptr, cursor, N_);
    k_fill<<<dim3((E_ + 255) / 256), dim3(256), 0, stream>>>(blk_src, blk_dst, E_, cursor, colsrc);

    // --- LSTM prep + run ---
    k_xtab<<<dim3(128, 2), dim3(512), 0, stream>>>(emb_url, Wih_f, b_f, Wih_b, b_b, xtab);
    {
        WtArgs a;
        a.seg[0] = {fc_lstm_W, wt_fclstm,            256, 256, 128, 1 * 128 * 256};
        a.seg[1] = {W0_self,   wt_w05s,              128, 128, 128, 4 * 128 * 128};
        a.seg[2] = {W0_neigh,  wt_w05n,              128, 128, 128, 4 * 128 * 128};
        a.seg[3] = {Wip_self,  wt_w05s + 4 * 16384,  128,  32, 128, 1 * 128 * 128};
        a.seg[4] = {Wip_neigh, wt_w05n + 4 * 16384,  128,  32, 128, 1 * 128 * 128};
        a.seg[5] = {W1_self,   wt_w1s,               128, 128, 128, 5 * 128 * 128};
        a.seg[6] = {W1_neigh,  wt_w1n,               128, 128, 128, 5 * 128 * 128};
        a.seg[7] = {attnlin_W, wt_attn,              128, 128, 128, 1 * 128 * 128};
        a.seg[8] = {fc_W,      wt_fc,                256, 256, 128, 1 * 128 * 256};
        k_wt_all<<<dim3((5 * 128 * 128 + 255) / 256, 9), dim3(256), 0, stream>>>(a);
    }
    // combined bias [5][128] = b0 (4x128) | bip (128)
    hipMemcpyAsync(bias5, b0, 512 * sizeof(float), hipMemcpyDeviceToDevice, stream);
    hipMemcpyAsync(bias5 + 512, bip, 128 * sizeof(float), hipMemcpyDeviceToDevice, stream);

    k_lstm<<<dim3(N_ / 16, 2), dim3(512), 0, stream>>>(xtab, inp_s, inp_sm, Whh_f, Whh_b, hcat);

    // vec_url = lrelu(hcat @ fc_lstm_W + b) -> F0 cols [0,128)
    k_gemm<1, 0><<<dim3((N_ + 63) / 64, 1), dim3(256), 0, stream>>>(
        hcat, 256, 0, nullptr, 0, 0, wt_fclstm, 0, nullptr, 0,
        fc_lstm_b, 0, F0, 544, 0, N_, 256);
    k_pack<<<dim3(N_), dim3(128), 0, stream>>>(inp_c, inp_co, inp_sl, inp_ip,
                                               emb_cat, emb_cou, emb_sl, F0);

    // --- SAGE layer 0: all 5 streams (ip K-padded to 128) in one dispatch ---
    k_agg<<<dim3(N_ / 4), dim3(256), 0, stream>>>(F0, 544, rowptr, colsrc, NEI, N_);
    k_gemm<1, 1><<<dim3((N_ + 63) / 64, 5), dim3(256), 0, stream>>>(
        F0, 544, 128, NEI, 544, 128, wt_w05s, 128 * 128, wt_w05n, 128 * 128,
        bias5, 128, F1, 640, 128, N_, 128);

    // --- SAGE layer 1 ---
    k_agg<<<dim3(N_ / 4), dim3(256), 0, stream>>>(F1, 640, rowptr, colsrc, NEI, N_);
    k_gemm<1, 1><<<dim3((N_ + 63) / 64, 5), dim3(256), 0, stream>>>(
        F1, 640, 128, NEI, 640, 128, wt_w1s, 128 * 128, wt_w1n, 128 * 128,
        b1, 128, H1, 640, 128, N_, 128);

    // --- attention ---
    // z: [N*5,128] = H1 @ attnlin_W  (H1 rows are exactly (n,s) pairs)
    k_gemm<0, 0><<<dim3((N_ * 5 + 63) / 64, 1), dim3(256), 0, stream>>>(
        H1, 128, 0, nullptr, 0, 0, wt_attn, 0, nullptr, 0,
        nullptr, 0, Zb, 128, 0, N_ * 5, 128);
    k_attn<<<dim3(N_ / 4), dim3(256), 0, stream>>>(Zb, attn_W, aA, hT, N_);

    // --- edge scoring (attn_e fused in) ---
    k_edge<<<dim3(E2_ / 64), dim3(256), 0, stream>>>(hT, e_src, e_dst, wt_fc, fc_b,
                                                     fco_W, fco_b, aA,
                                                     out_score, out_attne, E2_);
}